// Round 8
// baseline (2709.307 us; speedup 1.0000x reference)
//
#include <hip/hip_runtime.h>
#include <hip/hip_cooperative_groups.h>
#include <math.h>

namespace cg = cooperative_groups;

#define B_ 2
#define L_ 1024
#define D_ 768
#define NL_ 8
#define DI_ 1536
#define NS_ 16
#define DR_ 48
#define KC_ 4
#define EPS_ 1e-5f
#define M_ (B_*L_)   // 2048 rows
#define NC_ 32       // scan chunks
#define T_ 32        // chunk length (NC_*T_ == L_)
#define KS_ 16       // x_proj split-K factor
#define KCH_ (DI_/KS_)   // 96 per split
#define KDT_ 64          // dt GEMM padded K (48 -> 64)

typedef short bf16x8 __attribute__((ext_vector_type(8)));
typedef float f32x4  __attribute__((ext_vector_type(4)));

// ---------------- fp32 -> bf16 (RNE) ---------------------------------------
__device__ __forceinline__ unsigned short f2bf(float f) {
    union { float f; unsigned int u; } v; v.f = f;
    unsigned int u = v.u;
    u += 0x7fffu + ((u >> 16) & 1u);
    return (unsigned short)(u >> 16);
}

__device__ __forceinline__ unsigned int pk2(float a, float b) {
    union { float f; unsigned int u; } va, vb;
    va.f = a; vb.f = b;
    unsigned int ua = va.u + (0x7fffu + ((va.u >> 16) & 1u));
    unsigned int ub = vb.u + (0x7fffu + ((vb.u >> 16) & 1u));
    return (ua >> 16) | (ub & 0xffff0000u);
}

// async global->LDS, 16B per lane; LDS dest must be wave-uniform base + lane*16
__device__ __forceinline__ void gload16(const void* g, void* l) {
    __builtin_amdgcn_global_load_lds(
        (const __attribute__((address_space(1))) void*)g,
        (__attribute__((address_space(3))) void*)l, 16, 0, 0);
}

// ---------------- prep (clock-ramp-bound; structure frozen) -----------------
__device__ __forceinline__ void cvt_blk(const float* __restrict__ s,
                                        unsigned short* __restrict__ d, int tid) {
    int o = tid * 4;
    float4 a0 = *(const float4*)&s[o];
    float4 a1 = *(const float4*)&s[o + 1024];
    float4 a2 = *(const float4*)&s[o + 2048];
    float4 a3 = *(const float4*)&s[o + 3072];
    *(uint2*)&d[o]        = (uint2){pk2(a0.x, a0.y), pk2(a0.z, a0.w)};
    *(uint2*)&d[o + 1024] = (uint2){pk2(a1.x, a1.y), pk2(a1.z, a1.w)};
    *(uint2*)&d[o + 2048] = (uint2){pk2(a2.x, a2.y), pk2(a2.z, a2.w)};
    *(uint2*)&d[o + 3072] = (uint2){pk2(a3.x, a3.y), pk2(a3.z, a3.w)};
}

__global__ __launch_bounds__(256) void prep_kernel(
    const float* __restrict__ wi, unsigned short* __restrict__ wi_bf,
    const float* __restrict__ wo, unsigned short* __restrict__ wo_bf,
    const float* __restrict__ wx, unsigned short* __restrict__ wx_bf,
    const float* __restrict__ wdt, unsigned short* __restrict__ wdt_bf,
    const float* __restrict__ A_log, float* __restrict__ negA,
    const float* __restrict__ x, float* __restrict__ xcur,
    float* __restrict__ res,
    unsigned short* __restrict__ dbc_bf) {
    const int E0 = NL_ * 2 * DI_ * D_;   // 18874368 wi
    const int E1 = NL_ * D_ * DI_;       // 9437184  wo
    const int E2 = NL_ * 80 * DI_;       // 983040   wx
    const int E3 = NL_ * DI_ * KDT_;     // 786432   wdt
    const int E4 = NL_ * DI_ * NS_;      // 196608   negA
    const int E5 = M_ * D_;              // 1572864  init
    int tid = threadIdx.x;
    int base = blockIdx.x * 4096;
    if (base < E0) { cvt_blk(wi + base, wi_bf + base, tid); return; }
    base -= E0;
    if (base < E1) { cvt_blk(wo + base, wo_bf + base, tid); return; }
    base -= E1;
    if (base < E2) { cvt_blk(wx + base, wx_bf + base, tid); return; }
    base -= E2;
    if (base < E3) {                     // dt_w: K padded 48 -> 64
        int off0 = base + tid * 4;
        int col = off0 & (KDT_ - 1);
        if (col < DR_) {
            float4 a0 = *(const float4*)&wdt[(size_t)((off0) >> 6) * DR_ + col];
            float4 a1 = *(const float4*)&wdt[(size_t)((off0 + 1024) >> 6) * DR_ + col];
            float4 a2 = *(const float4*)&wdt[(size_t)((off0 + 2048) >> 6) * DR_ + col];
            float4 a3 = *(const float4*)&wdt[(size_t)((off0 + 3072) >> 6) * DR_ + col];
            *(uint2*)&wdt_bf[off0]        = (uint2){pk2(a0.x, a0.y), pk2(a0.z, a0.w)};
            *(uint2*)&wdt_bf[off0 + 1024] = (uint2){pk2(a1.x, a1.y), pk2(a1.z, a1.w)};
            *(uint2*)&wdt_bf[off0 + 2048] = (uint2){pk2(a2.x, a2.y), pk2(a2.z, a2.w)};
            *(uint2*)&wdt_bf[off0 + 3072] = (uint2){pk2(a3.x, a3.y), pk2(a3.z, a3.w)};
        } else {
            uint2 z = {0u, 0u};
            *(uint2*)&wdt_bf[off0] = z;
            *(uint2*)&wdt_bf[off0 + 1024] = z;
            *(uint2*)&wdt_bf[off0 + 2048] = z;
            *(uint2*)&wdt_bf[off0 + 3072] = z;
        }
        return;
    }
    base -= E3;
    if (base < E4) {                     // negA = -exp(A_log)
        int off0 = base + tid * 4;
        float4 a0 = *(const float4*)&A_log[off0];
        float4 a1 = *(const float4*)&A_log[off0 + 1024];
        float4 a2 = *(const float4*)&A_log[off0 + 2048];
        float4 a3 = *(const float4*)&A_log[off0 + 3072];
        *(float4*)&negA[off0] = make_float4(-__expf(a0.x), -__expf(a0.y), -__expf(a0.z), -__expf(a0.w));
        *(float4*)&negA[off0 + 1024] = make_float4(-__expf(a1.x), -__expf(a1.y), -__expf(a1.z), -__expf(a1.w));
        *(float4*)&negA[off0 + 2048] = make_float4(-__expf(a2.x), -__expf(a2.y), -__expf(a2.z), -__expf(a2.w));
        *(float4*)&negA[off0 + 3072] = make_float4(-__expf(a3.x), -__expf(a3.y), -__expf(a3.z), -__expf(a3.w));
        return;
    }
    base -= E4;
    if (base < E5) {                     // xcur = x; res = 0
        int off0 = base + tid * 4;
        float4 a0 = *(const float4*)&x[off0];
        float4 a1 = *(const float4*)&x[off0 + 1024];
        float4 a2 = *(const float4*)&x[off0 + 2048];
        float4 a3 = *(const float4*)&x[off0 + 3072];
        float4 z = make_float4(0.f, 0.f, 0.f, 0.f);
        *(float4*)&xcur[off0] = a0;        *(float4*)&res[off0] = z;
        *(float4*)&xcur[off0 + 1024] = a1; *(float4*)&res[off0 + 1024] = z;
        *(float4*)&xcur[off0 + 2048] = a2; *(float4*)&res[off0 + 2048] = z;
        *(float4*)&xcur[off0 + 3072] = a3; *(float4*)&res[off0 + 3072] = z;
        return;
    }
    base -= E5;
    {                                    // zero dbc_bf pad (cols >= 48 stay 0)
        int off0 = base + tid * 4;
        uint2 z = {0u, 0u};
        *(uint2*)&dbc_bf[off0] = z;
        *(uint2*)&dbc_bf[off0 + 1024] = z;
        *(uint2*)&dbc_bf[off0 + 2048] = z;
        *(uint2*)&dbc_bf[off0 + 3072] = z;
    }
}

// ---------------- wave-wide sum (64 lanes), result broadcast ----------------
__device__ __forceinline__ float wave_sum(float v) {
    #pragma unroll
    for (int o = 32; o > 0; o >>= 1) v += __shfl_down(v, o);
    return __shfl(v, 0);
}

// ---------------- fused residual-accumulate + LayerNorm (bf16 out) ----------
__global__ __launch_bounds__(256) void ln_res_kernel(
    const float* __restrict__ xcur, float* __restrict__ res,
    const float* __restrict__ w, const float* __restrict__ b,
    unsigned short* __restrict__ xn) {
    int wave = threadIdx.x >> 6, lane = threadIdx.x & 63;
    int row = blockIdx.x * 4 + wave;
    size_t base = (size_t)row * D_;
    int off = lane * 4;
    float4 v0 = *(const float4*)&xcur[base + off];
    float4 v1 = *(const float4*)&xcur[base + off + 256];
    float4 v2 = *(const float4*)&xcur[base + off + 512];
    float4 r0 = *(const float4*)&res[base + off];
    float4 r1 = *(const float4*)&res[base + off + 256];
    float4 r2 = *(const float4*)&res[base + off + 512];
    r0.x += v0.x; r0.y += v0.y; r0.z += v0.z; r0.w += v0.w;
    r1.x += v1.x; r1.y += v1.y; r1.z += v1.z; r1.w += v1.w;
    r2.x += v2.x; r2.y += v2.y; r2.z += v2.z; r2.w += v2.w;
    *(float4*)&res[base + off]       = r0;
    *(float4*)&res[base + off + 256] = r1;
    *(float4*)&res[base + off + 512] = r2;
    float s = (v0.x + v0.y + v0.z + v0.w) + (v1.x + v1.y + v1.z + v1.w)
            + (v2.x + v2.y + v2.z + v2.w);
    float mu = wave_sum(s) * (1.0f / D_);
    float4 d0 = make_float4(v0.x - mu, v0.y - mu, v0.z - mu, v0.w - mu);
    float4 d1 = make_float4(v1.x - mu, v1.y - mu, v1.z - mu, v1.w - mu);
    float4 d2 = make_float4(v2.x - mu, v2.y - mu, v2.z - mu, v2.w - mu);
    float sv = d0.x * d0.x + d0.y * d0.y + d0.z * d0.z + d0.w * d0.w
             + d1.x * d1.x + d1.y * d1.y + d1.z * d1.z + d1.w * d1.w
             + d2.x * d2.x + d2.y * d2.y + d2.z * d2.z + d2.w * d2.w;
    float var = wave_sum(sv) * (1.0f / D_);
    float rs = rsqrtf(var + EPS_);
    float4 w0 = *(const float4*)&w[off];
    float4 w1 = *(const float4*)&w[off + 256];
    float4 w2 = *(const float4*)&w[off + 512];
    float4 b0 = *(const float4*)&b[off];
    float4 b1 = *(const float4*)&b[off + 256];
    float4 b2 = *(const float4*)&b[off + 512];
    *(uint2*)&xn[base + off] = (uint2){
        pk2(d0.x * rs * w0.x + b0.x, d0.y * rs * w0.y + b0.y),
        pk2(d0.z * rs * w0.z + b0.z, d0.w * rs * w0.w + b0.w)};
    *(uint2*)&xn[base + off + 256] = (uint2){
        pk2(d1.x * rs * w1.x + b1.x, d1.y * rs * w1.y + b1.y),
        pk2(d1.z * rs * w1.z + b1.z, d1.w * rs * w1.w + b1.w)};
    *(uint2*)&xn[base + off + 512] = (uint2){
        pk2(d2.x * rs * w2.x + b2.x, d2.y * rs * w2.y + b2.y),
        pk2(d2.z * rs * w2.z + b2.z, d2.w * rs * w2.w + b2.w)};
}

// ---------------- final LN: out = LN(xcur + res), wave-per-row --------------
__global__ __launch_bounds__(256) void final_ln_kernel(
    const float* __restrict__ xcur, const float* __restrict__ res,
    const float* __restrict__ w, const float* __restrict__ b,
    float* __restrict__ out) {
    int wave = threadIdx.x >> 6, lane = threadIdx.x & 63;
    int row = blockIdx.x * 4 + wave;
    size_t base = (size_t)row * D_;
    int off = lane * 4;
    float4 v0 = *(const float4*)&xcur[base + off];
    float4 v1 = *(const float4*)&xcur[base + off + 256];
    float4 v2 = *(const float4*)&xcur[base + off + 512];
    float4 r0 = *(const float4*)&res[base + off];
    float4 r1 = *(const float4*)&res[base + off + 256];
    float4 r2 = *(const float4*)&res[base + off + 512];
    v0.x += r0.x; v0.y += r0.y; v0.z += r0.z; v0.w += r0.w;
    v1.x += r1.x; v1.y += r1.y; v1.z += r1.z; v1.w += r1.w;
    v2.x += r2.x; v2.y += r2.y; v2.z += r2.z; v2.w += r2.w;
    float s = (v0.x + v0.y + v0.z + v0.w) + (v1.x + v1.y + v1.z + v1.w)
            + (v2.x + v2.y + v2.z + v2.w);
    float mu = wave_sum(s) * (1.0f / D_);
    float4 d0 = make_float4(v0.x - mu, v0.y - mu, v0.z - mu, v0.w - mu);
    float4 d1 = make_float4(v1.x - mu, v1.y - mu, v1.z - mu, v1.w - mu);
    float4 d2 = make_float4(v2.x - mu, v2.y - mu, v2.z - mu, v2.w - mu);
    float sv = d0.x * d0.x + d0.y * d0.y + d0.z * d0.z + d0.w * d0.w
             + d1.x * d1.x + d1.y * d1.y + d1.z * d1.z + d1.w * d1.w
             + d2.x * d2.x + d2.y * d2.y + d2.z * d2.z + d2.w * d2.w;
    float var = wave_sum(sv) * (1.0f / D_);
    float rs = rsqrtf(var + EPS_);
    float4 w0 = *(const float4*)&w[off];
    float4 w1 = *(const float4*)&w[off + 256];
    float4 w2 = *(const float4*)&w[off + 512];
    float4 b0 = *(const float4*)&b[off];
    float4 b1 = *(const float4*)&b[off + 256];
    float4 b2 = *(const float4*)&b[off + 512];
    *(float4*)&out[base + off] = make_float4(
        d0.x * rs * w0.x + b0.x, d0.y * rs * w0.y + b0.y,
        d0.z * rs * w0.z + b0.z, d0.w * rs * w0.w + b0.w);
    *(float4*)&out[base + off + 256] = make_float4(
        d1.x * rs * w1.x + b1.x, d1.y * rs * w1.y + b1.y,
        d1.z * rs * w1.z + b1.z, d1.w * rs * w1.w + b1.w);
    *(float4*)&out[base + off + 512] = make_float4(
        d2.x * rs * w2.x + b2.x, d2.y * rs * w2.y + b2.y,
        d2.z * rs * w2.z + b2.z, d2.w * rs * w2.w + b2.w);
}

// ---------------- bf16 MFMA GEMM: C[M,N] = A[M,K] * W[N,K]^T ---------------
template <int BM, int BN>
__global__ __launch_bounds__(256) void gemm_bf16_t(
    const unsigned short* __restrict__ A,   // M x K bf16 row-major
    const unsigned short* __restrict__ W,   // N x K bf16 row-major
    float* __restrict__ C, int M, int N, int K) {
    constexpr int FM = BM / 32;
    constexpr int FN = BN / 32;
    constexpr int NLD = (BM + BN) / 64;
    __shared__ unsigned short sA[BM * 32];
    __shared__ unsigned short sW[BN * 32];
    int bm = blockIdx.y * BM, bn = blockIdx.x * BN;
    int tid = threadIdx.x;
    int wave = tid >> 6, lane = tid & 63;
    int wrow = (wave & 1) * (BM / 2), wcol = (wave >> 1) * (BN / 2);
    int quad = lane >> 4, r16 = lane & 15;
    f32x4 acc[FM][FN];
    #pragma unroll
    for (int i = 0; i < FM; i++)
        #pragma unroll
        for (int j = 0; j < FN; j++)
            acc[i][j] = (f32x4){0.f, 0.f, 0.f, 0.f};

    for (int k0 = 0; k0 < K; k0 += 32) {
        #pragma unroll
        for (int r = 0; r < NLD; r++) {
            if (r < BM / 64) {
                int j = r * 256 + tid;
                gload16(&A[(size_t)(bm + (j >> 2)) * K + k0 + (j & 3) * 8],
                        &sA[(r * 256 + wave * 64) * 8]);
            } else {
                int j = (r - BM / 64) * 256 + tid;
                gload16(&W[(size_t)(bn + (j >> 2)) * K + k0 + (j & 3) * 8],
                        &sW[((r - BM / 64) * 256 + wave * 64) * 8]);
            }
        }
        __syncthreads();
        bf16x8 af[FM], wf[FN];
        #pragma unroll
        for (int i = 0; i < FM; i++)
            af[i] = *(const bf16x8*)&sA[(wrow + i * 16 + r16) * 32 + quad * 8];
        #pragma unroll
        for (int j = 0; j < FN; j++)
            wf[j] = *(const bf16x8*)&sW[(wcol + j * 16 + r16) * 32 + quad * 8];
        #pragma unroll
        for (int i = 0; i < FM; i++)
            #pragma unroll
            for (int j = 0; j < FN; j++)
                acc[i][j] = __builtin_amdgcn_mfma_f32_16x16x32_bf16(
                    af[i], wf[j], acc[i][j], 0, 0, 0);
        __syncthreads();
    }
    #pragma unroll
    for (int i = 0; i < FM; i++) {
        #pragma unroll
        for (int j = 0; j < FN; j++) {
            int col = bn + wcol + j * 16 + r16;
            #pragma unroll
            for (int reg = 0; reg < 4; reg++) {
                int row = bm + wrow + i * 16 + quad * 4 + reg;
                C[(size_t)row * N + col] = acc[i][j][reg];
            }
        }
    }
}

// ---------------- dt GEMM bf16 MFMA (M=2048, N=DI, K=64 padded) -------------
__global__ __launch_bounds__(256) void dt_gemm_bf16(
    const unsigned short* __restrict__ A,
    const unsigned short* __restrict__ W,
    const float* __restrict__ bias,
    float* __restrict__ dtb) {
    __shared__ unsigned short sA[128 * 32];
    __shared__ unsigned short sW[128 * 32];
    int bm = blockIdx.y * 128, bn = blockIdx.x * 128;
    int tid = threadIdx.x;
    int wave = tid >> 6, lane = tid & 63;
    int wrow = (wave & 1) * 64, wcol = (wave >> 1) * 64;
    int quad = lane >> 4, r16 = lane & 15;
    f32x4 acc[4][4];
    #pragma unroll
    for (int i = 0; i < 4; i++)
        #pragma unroll
        for (int j = 0; j < 4; j++)
            acc[i][j] = (f32x4){0.f, 0.f, 0.f, 0.f};

    #pragma unroll
    for (int k0 = 0; k0 < KDT_; k0 += 32) {
        #pragma unroll
        for (int r = 0; r < 4; r++) {
            if (r < 2) {
                int j = r * 256 + tid;
                gload16(&A[(size_t)(bm + (j >> 2)) * KDT_ + k0 + (j & 3) * 8],
                        &sA[(r * 256 + wave * 64) * 8]);
            } else {
                int j = (r - 2) * 256 + tid;
                gload16(&W[(size_t)(bn + (j >> 2)) * KDT_ + k0 + (j & 3) * 8],
                        &sW[((r - 2) * 256 + wave * 64) * 8]);
            }
        }
        __syncthreads();
        bf16x8 af[4], wf[4];
        #pragma unroll
        for (int i = 0; i < 4; i++)
            af[i] = *(const bf16x8*)&sA[(wrow + i * 16 + r16) * 32 + quad * 8];
        #pragma unroll
        for (int j = 0; j < 4; j++)
            wf[j] = *(const bf16x8*)&sW[(wcol + j * 16 + r16) * 32 + quad * 8];
        #pragma unroll
        for (int i = 0; i < 4; i++)
            #pragma unroll
            for (int j = 0; j < 4; j++)
                acc[i][j] = __builtin_amdgcn_mfma_f32_16x16x32_bf16(
                    af[i], wf[j], acc[i][j], 0, 0, 0);
        __syncthreads();
    }
    #pragma unroll
    for (int i = 0; i < 4; i++) {
        #pragma unroll
        for (int j = 0; j < 4; j++) {
            int col = bn + wcol + j * 16 + r16;
            float bv = bias[col];
            #pragma unroll
            for (int reg = 0; reg < 4; reg++) {
                int row = bm + wrow + i * 16 + quad * 4 + reg;
                float v = acc[i][j][reg] + bv;
                v = (v > 20.f) ? v : log1pf(__expf(v));
                dtb[(size_t)row * DI_ + col] = v;
            }
        }
    }
}

// ---------------- fused conv+SiLU+x_proj GEMM (split-K over ks) -------------
__global__ __launch_bounds__(256) void conv_xproj_kernel(
    const float* __restrict__ xz,
    const float* __restrict__ cw,
    const float* __restrict__ cb,
    const unsigned short* __restrict__ W,
    float* __restrict__ xcf,
    float* __restrict__ Pb) {
    __shared__ float sxz[67 * 96];
    __shared__ unsigned short sxcb[64 * 104];
    __shared__ float scw[96 * 4];
    __shared__ float scb[96];
    unsigned short* sW = (unsigned short*)sxz;

    int ks = blockIdx.x;
    int bm = blockIdx.y * 64;
    int tid = threadIdx.x;
    int b = bm >> 10, t0 = bm & (L_ - 1);
    int dbase = ks * KCH_;

    if (tid < 96) {
        int d = dbase + tid;
        *(float4*)&scw[tid * 4] = *(const float4*)&cw[d * 4];
        scb[tid] = cb[d];
    }
    for (int j = tid; j < 67 * 24; j += 256) {
        int r = j / 24, c4 = (j % 24) * 4;
        int tt = t0 + r - 3;
        float4 v = make_float4(0.f, 0.f, 0.f, 0.f);
        if (tt >= 0)
            v = *(const float4*)&xz[((size_t)(b * L_ + tt)) * (2 * DI_) + dbase + c4];
        *(float4*)&sxz[r * 96 + c4] = v;
    }
    __syncthreads();
    for (int j = tid; j < 64 * 96; j += 256) {
        int r = j / 96, c = j % 96;
        float acc = scb[c];
        #pragma unroll
        for (int k = 0; k < KC_; k++)
            acc = fmaf(scw[c * 4 + k], sxz[(r + k) * 96 + c], acc);
        float v = acc / (1.0f + __expf(-acc));
        xcf[(size_t)(bm + r) * DI_ + dbase + c] = v;
        sxcb[r * 104 + c] = f2bf(v);
    }
    __syncthreads();
    for (int j = tid; j < 80 * 12; j += 256) {
        int row = j / 12, c16 = (j % 12) * 8;
        *(uint4*)&sW[row * 104 + c16] =
            *(const uint4*)&W[(size_t)row * DI_ + dbase + c16];
    }
    __syncthreads();
    int wave = tid >> 6, lane = tid & 63;
    int quad = lane >> 4, r16 = lane & 15;
    f32x4 acc[5];
    #pragma unroll
    for (int j = 0; j < 5; j++) acc[j] = (f32x4){0.f, 0.f, 0.f, 0.f};
    #pragma unroll
    for (int kk = 0; kk < 3; kk++) {
        bf16x8 af = *(const bf16x8*)&sxcb[(wave * 16 + r16) * 104 + kk * 32 + quad * 8];
        #pragma unroll
        for (int j = 0; j < 5; j++) {
            bf16x8 wf = *(const bf16x8*)&sW[(j * 16 + r16) * 104 + kk * 32 + quad * 8];
            acc[j] = __builtin_amdgcn_mfma_f32_16x16x32_bf16(af, wf, acc[j], 0, 0, 0);
        }
    }
    #pragma unroll
    for (int j = 0; j < 5; j++) {
        int col = j * 16 + r16;
        #pragma unroll
        for (int reg = 0; reg < 4; reg++) {
            int row = bm + wave * 16 + quad * 4 + reg;
            Pb[((size_t)ks * M_ + row) * 80 + col] = acc[j][reg];
        }
    }
}

// reduce split-K partials; scatter into dbc_bf (M x 64 bf16) and packed BC
__global__ void xproj_reduce_kernel(const float* __restrict__ Pb,
                                    unsigned short* __restrict__ dbc_bf,
                                    float* __restrict__ bcp) {
    int i = blockIdx.x * 256 + threadIdx.x;   // over M_*80
    float s = 0.f;
    #pragma unroll
    for (int ks = 0; ks < KS_; ks++) s += Pb[(size_t)ks * (M_ * 80) + i];
    int m = i / 80, col = i % 80;
    if (col < DR_) {
        dbc_bf[m * KDT_ + col] = f2bf(s);
    } else if (col < DR_ + NS_) {
        bcp[m * 32 + 2 * (col - DR_)] = s;         // B_n
    } else {
        bcp[m * 32 + 2 * (col - DR_ - NS_) + 1] = s; // C_n
    }
}

// ---------------- FUSED scan: summaries -> combine -> output, one kernel ----
// Cooperative launch; grid = B*NC*(DI/128) = 768 blocks x 128 threads
// (2 waves/block, ~3 blocks/CU -> co-residency guaranteed).
// Phase 3 re-reads each block's own dtb/xcf slice: 32 KB/block, ~3 MB/XCD,
// L2-warm after phase 1 (block stays on its CU across grid.sync()).
__global__ __launch_bounds__(128) void scan_fused_kernel(
    const float* __restrict__ dtb, const float* __restrict__ xcf,
    const float4* __restrict__ bcp4, const float* __restrict__ negA,
    float* __restrict__ Sb, float* __restrict__ sdb,
    float* __restrict__ hin, const float* __restrict__ xz,
    const float* __restrict__ Dp, unsigned short* __restrict__ yg) {
    cg::grid_group grid = cg::this_grid();
    const int NDB = DI_ / 128;         // 12 d-blocks
    int bx = blockIdx.x;
    int dblk = bx % NDB;
    int c = (bx / NDB) % NC_;
    int b = bx / (NDB * NC_);
    int d = dblk * 128 + threadIdx.x;

    float A[NS_];
    #pragma unroll
    for (int n = 0; n < NS_; n++) A[n] = negA[(size_t)d * NS_ + n];

    size_t btbase = (size_t)(b * L_ + c * T_);
    const float* pdt = dtb + btbase * DI_ + d;
    const float* pxc = xcf + btbase * DI_ + d;
    const float4* pbc = bcp4 + btbase * 8;

    // ---- phase 1: per-chunk summaries ----
    {
        float h[NS_];
        #pragma unroll
        for (int n = 0; n < NS_; n++) h[n] = 0.f;
        float sd = 0.f;
        #pragma unroll 4
        for (int t = 0; t < T_; t++) {
            float dt = pdt[(size_t)t * DI_];
            float u  = dt * pxc[(size_t)t * DI_];
            sd += dt;
            #pragma unroll
            for (int q = 0; q < 8; q++) {
                float4 v = pbc[t * 8 + q];
                float e0 = __expf(dt * A[2 * q]);
                h[2 * q] = fmaf(e0, h[2 * q], u * v.x);
                float e1 = __expf(dt * A[2 * q + 1]);
                h[2 * q + 1] = fmaf(e1, h[2 * q + 1], u * v.z);
            }
        }
        size_t o = (((size_t)b * NC_ + c) * DI_ + d) * NS_;
        #pragma unroll
        for (int n = 0; n < NS_; n++) Sb[o + n] = h[n];
        sdb[((size_t)b * NC_ + c) * DI_ + d] = sd;
    }

    grid.sync();

    // ---- phase 2: sequential combine (first B*DI*NS threads) ----
    {
        int i = blockIdx.x * 128 + threadIdx.x;
        if (i < B_ * DI_ * NS_) {
            int bb = i / (DI_ * NS_);
            int rem = i % (DI_ * NS_);
            int dd = rem >> 4;
            float Aa = negA[rem];
            const size_t str = (size_t)DI_ * NS_;
            size_t o = (size_t)bb * NC_ * str + rem;
            size_t osd = (size_t)bb * NC_ * DI_ + dd;
            float h = 0.f;
            float s0 = Sb[o],           sd0 = sdb[osd];
            float s1 = Sb[o + str],     sd1 = sdb[osd + DI_];
            float s2 = Sb[o + 2 * str], sd2 = sdb[osd + 2 * DI_];
            float s3 = Sb[o + 3 * str], sd3 = sdb[osd + 3 * DI_];
            for (int cc = 0; cc < NC_ - 4; cc += 4) {
                float n0 = Sb[o + 4 * str], nd0 = sdb[osd + 4 * DI_];
                float n1 = Sb[o + 5 * str], nd1 = sdb[osd + 5 * DI_];
                float n2 = Sb[o + 6 * str], nd2 = sdb[osd + 6 * DI_];
                float n3 = Sb[o + 7 * str], nd3 = sdb[osd + 7 * DI_];
                hin[o] = h;           h = fmaf(__expf(Aa * sd0), h, s0);
                hin[o + str] = h;     h = fmaf(__expf(Aa * sd1), h, s1);
                hin[o + 2 * str] = h; h = fmaf(__expf(Aa * sd2), h, s2);
                hin[o + 3 * str] = h; h = fmaf(__expf(Aa * sd3), h, s3);
                s0 = n0; sd0 = nd0; s1 = n1; sd1 = nd1;
                s2 = n2; sd2 = nd2; s3 = n3; sd3 = nd3;
                o += 4 * str; osd += 4 * DI_;
            }
            hin[o] = h;           h = fmaf(__expf(Aa * sd0), h, s0);
            hin[o + str] = h;     h = fmaf(__expf(Aa * sd1), h, s1);
            hin[o + 2 * str] = h; h = fmaf(__expf(Aa * sd2), h, s2);
            hin[o + 3 * str] = h;
        }
    }

    grid.sync();

    // ---- phase 3: exact recurrence from hin -> yg ----
    {
        size_t o = (((size_t)b * NC_ + c) * DI_ + d) * NS_;
        float h[NS_];
        #pragma unroll
        for (int n = 0; n < NS_; n++) h[n] = hin[o + n];
        float dpv = Dp[d];
        #pragma unroll 4
        for (int t = 0; t < T_; t++) {
            float dt = pdt[(size_t)t * DI_];
            float xc = pxc[(size_t)t * DI_];
            float u = dt * xc;
            float y = 0.f;
            #pragma unroll
            for (int q = 0; q < 8; q++) {
                float4 v = pbc[t * 8 + q];
                float e0 = __expf(dt * A[2 * q]);
                h[2 * q] = fmaf(e0, h[2 * q], u * v.x);
                y = fmaf(v.y, h[2 * q], y);
                float e1 = __expf(dt * A[2 * q + 1]);
                h[2 * q + 1] = fmaf(e1, h[2 * q + 1], u * v.z);
                y = fmaf(v.w, h[2 * q + 1], y);
            }
            size_t row = btbase + t;
            float zv = xz[row * (2 * DI_) + DI_ + d];
            float yy = y + xc * dpv;
            yy *= zv / (1.0f + __expf(-zv));
            yg[row * DI_ + d] = f2bf(yy);
        }
    }
}

extern "C" void kernel_launch(void* const* d_in, const int* in_sizes, int n_in,
                              void* d_out, int out_size, void* d_ws, size_t ws_size,
                              hipStream_t stream) {
    const float* x        = (const float*)d_in[0];
    const float* ln_w     = (const float*)d_in[1];
    const float* ln_b     = (const float*)d_in[2];
    const float* in_proj  = (const float*)d_in[3];
    const float* conv_w   = (const float*)d_in[4];
    const float* conv_b   = (const float*)d_in[5];
    const float* x_proj   = (const float*)d_in[6];
    const float* dt_w     = (const float*)d_in[7];
    const float* dt_b     = (const float*)d_in[8];
    const float* A_log    = (const float*)d_in[9];
    const float* D_skip   = (const float*)d_in[10];
    const float* out_proj = (const float*)d_in[11];
    const float* fn_w     = (const float*)d_in[12];
    const float* fn_b     = (const float*)d_in[13];
    float* out = (float*)d_out;

    char* p = (char*)d_ws;
    auto alloc = [&](size_t bytes) {
        char* r = p;
        p += (bytes + 255) & ~(size_t)255;
        return (void*)r;
    };
    float* xcur = (float*)alloc((size_t)M_ * D_ * 4);
    float* res  = (float*)alloc((size_t)M_ * D_ * 4);
    unsigned short* xn = (unsigned short*)alloc((size_t)M_ * D_ * 2);
    float* xz   = (float*)alloc((size_t)M_ * 2 * DI_ * 4);
    float* dtb  = (float*)alloc((size_t)M_ * DI_ * 4);
    float* xcf  = (float*)alloc((size_t)M_ * DI_ * 4);
    unsigned short* dbc_bf = (unsigned short*)alloc((size_t)M_ * KDT_ * 2);
    float* bcp  = (float*)alloc((size_t)M_ * 32 * 4);
    unsigned short* yg = (unsigned short*)alloc((size_t)M_ * DI_ * 2);
    float* Sb   = (float*)alloc((size_t)B_ * NC_ * DI_ * NS_ * 4);   // 6.3 MB
    float* sdb  = (float*)alloc((size_t)B_ * NC_ * DI_ * 4);         // 0.4 MB
    float* hin  = (float*)alloc((size_t)B_ * NC_ * DI_ * NS_ * 4);
    float* Pb   = (float*)alloc((size_t)KS_ * M_ * 80 * 4);
    float* negA = (float*)alloc((size_t)NL_ * DI_ * NS_ * 4);
    const size_t n_wi = (size_t)NL_ * 2 * DI_ * D_;
    const size_t n_wo = (size_t)NL_ * D_ * DI_;
    const size_t n_wx = (size_t)NL_ * 80 * DI_;
    const size_t n_wdt = (size_t)NL_ * DI_ * KDT_;
    unsigned short* wi_bf = (unsigned short*)alloc(n_wi * 2);
    unsigned short* wo_bf = (unsigned short*)alloc(n_wo * 2);
    unsigned short* wx_bf = (unsigned short*)alloc(n_wx * 2);
    unsigned short* wdt_bf = (unsigned short*)alloc(n_wdt * 2);

    prep_kernel<<<7808, 256, 0, stream>>>(
        in_proj, wi_bf, out_proj, wo_bf, x_proj, wx_bf,
        dt_w, wdt_bf, A_log, negA, x, xcur, res, dbc_bf);

    for (int l = 0; l < NL_; l++) {
        const float* negA_l = negA + (size_t)l * DI_ * NS_;
        const float* Dp_l = D_skip + (size_t)l * DI_;

        ln_res_kernel<<<M_ / 4, 256, 0, stream>>>(
            xcur, res, ln_w + l * D_, ln_b + l * D_, xn);

        // xz = xn @ Wi^T  (M=2048, N=3072, K=768): 128x64 -> 768 blocks (3/CU)
        gemm_bf16_t<128, 64><<<dim3((2 * DI_) / 64, M_ / 128), 256, 0, stream>>>(
            xn, wi_bf + (size_t)l * 2 * DI_ * D_, xz, M_, 2 * DI_, D_);

        conv_xproj_kernel<<<dim3(KS_, M_ / 64), 256, 0, stream>>>(
            xz, conv_w + l * DI_ * KC_, conv_b + l * DI_,
            wx_bf + (size_t)l * 80 * DI_, xcf, Pb);
        xproj_reduce_kernel<<<(M_ * 80) / 256, 256, 0, stream>>>(Pb, dbc_bf, bcp);

        dt_gemm_bf16<<<dim3(DI_ / 128, M_ / 128), 256, 0, stream>>>(
            dbc_bf, wdt_bf + (size_t)l * DI_ * KDT_, dt_b + l * DI_, dtb);

        // fused scan: 3 dispatches -> 1 cooperative dispatch
        {
            const float4* bcp4 = (const float4*)bcp;
            void* args[] = {
                (void*)&dtb, (void*)&xcf, (void*)&bcp4, (void*)&negA_l,
                (void*)&Sb, (void*)&sdb, (void*)&hin, (void*)&xz,
                (void*)&Dp_l, (void*)&yg };
            hipLaunchCooperativeKernel((void*)scan_fused_kernel,
                dim3(B_ * NC_ * (DI_ / 128)), dim3(128), args, 0, stream);
        }

        // xcur = yg @ Wo^T  (M=2048, N=768, K=1536): 64x64 -> 384 blocks
        gemm_bf16_t<64, 64><<<dim3(D_ / 64, M_ / 64), 256, 0, stream>>>(
            yg, wo_bf + (size_t)l * D_ * DI_, xcur, M_, D_, DI_);
    }

    final_ln_kernel<<<M_ / 4, 256, 0, stream>>>(xcur, res, fn_w, fn_b, out);
}

// Round 9
// 1190.722 us; speedup vs baseline: 2.2753x; 2.2753x over previous
//
#include <hip/hip_runtime.h>
#include <math.h>

#define B_ 2
#define L_ 1024
#define D_ 768
#define NL_ 8
#define DI_ 1536
#define NS_ 16
#define DR_ 48
#define KC_ 4
#define EPS_ 1e-5f
#define M_ (B_*L_)   // 2048 rows
#define NC_ 32       // scan chunks
#define T_ 32        // chunk length (NC_*T_ == L_)
#define KS_ 16       // x_proj split-K factor
#define KCH_ (DI_/KS_)   // 96 per split
#define KDT_ 64          // dt GEMM padded K (48 -> 64)

typedef short bf16x8 __attribute__((ext_vector_type(8)));
typedef float f32x4  __attribute__((ext_vector_type(4)));

// ---------------- fp32 -> bf16 (RNE) ---------------------------------------
__device__ __forceinline__ unsigned short f2bf(float f) {
    union { float f; unsigned int u; } v; v.f = f;
    unsigned int u = v.u;
    u += 0x7fffu + ((u >> 16) & 1u);
    return (unsigned short)(u >> 16);
}

__device__ __forceinline__ unsigned int pk2(float a, float b) {
    union { float f; unsigned int u; } va, vb;
    va.f = a; vb.f = b;
    unsigned int ua = va.u + (0x7fffu + ((va.u >> 16) & 1u));
    unsigned int ub = vb.u + (0x7fffu + ((vb.u >> 16) & 1u));
    return (ua >> 16) | (ub & 0xffff0000u);
}

// async global->LDS, 16B per lane; LDS dest must be wave-uniform base + lane*16
__device__ __forceinline__ void gload16(const void* g, void* l) {
    __builtin_amdgcn_global_load_lds(
        (const __attribute__((address_space(1))) void*)g,
        (__attribute__((address_space(3))) void*)l, 16, 0, 0);
}

// ---------------- prep (clock-ramp-bound; structure frozen) -----------------
__device__ __forceinline__ void cvt_blk(const float* __restrict__ s,
                                        unsigned short* __restrict__ d, int tid) {
    int o = tid * 4;
    float4 a0 = *(const float4*)&s[o];
    float4 a1 = *(const float4*)&s[o + 1024];
    float4 a2 = *(const float4*)&s[o + 2048];
    float4 a3 = *(const float4*)&s[o + 3072];
    *(uint2*)&d[o]        = (uint2){pk2(a0.x, a0.y), pk2(a0.z, a0.w)};
    *(uint2*)&d[o + 1024] = (uint2){pk2(a1.x, a1.y), pk2(a1.z, a1.w)};
    *(uint2*)&d[o + 2048] = (uint2){pk2(a2.x, a2.y), pk2(a2.z, a2.w)};
    *(uint2*)&d[o + 3072] = (uint2){pk2(a3.x, a3.y), pk2(a3.z, a3.w)};
}

__global__ __launch_bounds__(256) void prep_kernel(
    const float* __restrict__ wi, unsigned short* __restrict__ wi_bf,
    const float* __restrict__ wo, unsigned short* __restrict__ wo_bf,
    const float* __restrict__ wx, unsigned short* __restrict__ wx_bf,
    const float* __restrict__ wdt, unsigned short* __restrict__ wdt_bf,
    const float* __restrict__ A_log, float* __restrict__ negA,
    const float* __restrict__ x, float* __restrict__ xcur,
    float* __restrict__ res,
    unsigned short* __restrict__ dbc_bf) {
    const int E0 = NL_ * 2 * DI_ * D_;   // 18874368 wi
    const int E1 = NL_ * D_ * DI_;       // 9437184  wo
    const int E2 = NL_ * 80 * DI_;       // 983040   wx
    const int E3 = NL_ * DI_ * KDT_;     // 786432   wdt
    const int E4 = NL_ * DI_ * NS_;      // 196608   negA
    const int E5 = M_ * D_;              // 1572864  init
    int tid = threadIdx.x;
    int base = blockIdx.x * 4096;
    if (base < E0) { cvt_blk(wi + base, wi_bf + base, tid); return; }
    base -= E0;
    if (base < E1) { cvt_blk(wo + base, wo_bf + base, tid); return; }
    base -= E1;
    if (base < E2) { cvt_blk(wx + base, wx_bf + base, tid); return; }
    base -= E2;
    if (base < E3) {                     // dt_w: K padded 48 -> 64
        int off0 = base + tid * 4;
        int col = off0 & (KDT_ - 1);
        if (col < DR_) {
            float4 a0 = *(const float4*)&wdt[(size_t)((off0) >> 6) * DR_ + col];
            float4 a1 = *(const float4*)&wdt[(size_t)((off0 + 1024) >> 6) * DR_ + col];
            float4 a2 = *(const float4*)&wdt[(size_t)((off0 + 2048) >> 6) * DR_ + col];
            float4 a3 = *(const float4*)&wdt[(size_t)((off0 + 3072) >> 6) * DR_ + col];
            *(uint2*)&wdt_bf[off0]        = (uint2){pk2(a0.x, a0.y), pk2(a0.z, a0.w)};
            *(uint2*)&wdt_bf[off0 + 1024] = (uint2){pk2(a1.x, a1.y), pk2(a1.z, a1.w)};
            *(uint2*)&wdt_bf[off0 + 2048] = (uint2){pk2(a2.x, a2.y), pk2(a2.z, a2.w)};
            *(uint2*)&wdt_bf[off0 + 3072] = (uint2){pk2(a3.x, a3.y), pk2(a3.z, a3.w)};
        } else {
            uint2 z = {0u, 0u};
            *(uint2*)&wdt_bf[off0] = z;
            *(uint2*)&wdt_bf[off0 + 1024] = z;
            *(uint2*)&wdt_bf[off0 + 2048] = z;
            *(uint2*)&wdt_bf[off0 + 3072] = z;
        }
        return;
    }
    base -= E3;
    if (base < E4) {                     // negA = -exp(A_log)
        int off0 = base + tid * 4;
        float4 a0 = *(const float4*)&A_log[off0];
        float4 a1 = *(const float4*)&A_log[off0 + 1024];
        float4 a2 = *(const float4*)&A_log[off0 + 2048];
        float4 a3 = *(const float4*)&A_log[off0 + 3072];
        *(float4*)&negA[off0] = make_float4(-__expf(a0.x), -__expf(a0.y), -__expf(a0.z), -__expf(a0.w));
        *(float4*)&negA[off0 + 1024] = make_float4(-__expf(a1.x), -__expf(a1.y), -__expf(a1.z), -__expf(a1.w));
        *(float4*)&negA[off0 + 2048] = make_float4(-__expf(a2.x), -__expf(a2.y), -__expf(a2.z), -__expf(a2.w));
        *(float4*)&negA[off0 + 3072] = make_float4(-__expf(a3.x), -__expf(a3.y), -__expf(a3.z), -__expf(a3.w));
        return;
    }
    base -= E4;
    if (base < E5) {                     // xcur = x; res = 0
        int off0 = base + tid * 4;
        float4 a0 = *(const float4*)&x[off0];
        float4 a1 = *(const float4*)&x[off0 + 1024];
        float4 a2 = *(const float4*)&x[off0 + 2048];
        float4 a3 = *(const float4*)&x[off0 + 3072];
        float4 z = make_float4(0.f, 0.f, 0.f, 0.f);
        *(float4*)&xcur[off0] = a0;        *(float4*)&res[off0] = z;
        *(float4*)&xcur[off0 + 1024] = a1; *(float4*)&res[off0 + 1024] = z;
        *(float4*)&xcur[off0 + 2048] = a2; *(float4*)&res[off0 + 2048] = z;
        *(float4*)&xcur[off0 + 3072] = a3; *(float4*)&res[off0 + 3072] = z;
        return;
    }
    base -= E5;
    {                                    // zero dbc_bf pad (cols >= 48 stay 0)
        int off0 = base + tid * 4;
        uint2 z = {0u, 0u};
        *(uint2*)&dbc_bf[off0] = z;
        *(uint2*)&dbc_bf[off0 + 1024] = z;
        *(uint2*)&dbc_bf[off0 + 2048] = z;
        *(uint2*)&dbc_bf[off0 + 3072] = z;
    }
}

// ---------------- wave-wide sum (64 lanes), result broadcast ----------------
__device__ __forceinline__ float wave_sum(float v) {
    #pragma unroll
    for (int o = 32; o > 0; o >>= 1) v += __shfl_down(v, o);
    return __shfl(v, 0);
}

// ---------------- fused residual-accumulate + LayerNorm (bf16 out) ----------
__global__ __launch_bounds__(256) void ln_res_kernel(
    const float* __restrict__ xcur, float* __restrict__ res,
    const float* __restrict__ w, const float* __restrict__ b,
    unsigned short* __restrict__ xn) {
    int wave = threadIdx.x >> 6, lane = threadIdx.x & 63;
    int row = blockIdx.x * 4 + wave;
    size_t base = (size_t)row * D_;
    int off = lane * 4;
    float4 v0 = *(const float4*)&xcur[base + off];
    float4 v1 = *(const float4*)&xcur[base + off + 256];
    float4 v2 = *(const float4*)&xcur[base + off + 512];
    float4 r0 = *(const float4*)&res[base + off];
    float4 r1 = *(const float4*)&res[base + off + 256];
    float4 r2 = *(const float4*)&res[base + off + 512];
    r0.x += v0.x; r0.y += v0.y; r0.z += v0.z; r0.w += v0.w;
    r1.x += v1.x; r1.y += v1.y; r1.z += v1.z; r1.w += v1.w;
    r2.x += v2.x; r2.y += v2.y; r2.z += v2.z; r2.w += v2.w;
    *(float4*)&res[base + off]       = r0;
    *(float4*)&res[base + off + 256] = r1;
    *(float4*)&res[base + off + 512] = r2;
    float s = (v0.x + v0.y + v0.z + v0.w) + (v1.x + v1.y + v1.z + v1.w)
            + (v2.x + v2.y + v2.z + v2.w);
    float mu = wave_sum(s) * (1.0f / D_);
    float4 d0 = make_float4(v0.x - mu, v0.y - mu, v0.z - mu, v0.w - mu);
    float4 d1 = make_float4(v1.x - mu, v1.y - mu, v1.z - mu, v1.w - mu);
    float4 d2 = make_float4(v2.x - mu, v2.y - mu, v2.z - mu, v2.w - mu);
    float sv = d0.x * d0.x + d0.y * d0.y + d0.z * d0.z + d0.w * d0.w
             + d1.x * d1.x + d1.y * d1.y + d1.z * d1.z + d1.w * d1.w
             + d2.x * d2.x + d2.y * d2.y + d2.z * d2.z + d2.w * d2.w;
    float var = wave_sum(sv) * (1.0f / D_);
    float rs = rsqrtf(var + EPS_);
    float4 w0 = *(const float4*)&w[off];
    float4 w1 = *(const float4*)&w[off + 256];
    float4 w2 = *(const float4*)&w[off + 512];
    float4 b0 = *(const float4*)&b[off];
    float4 b1 = *(const float4*)&b[off + 256];
    float4 b2 = *(const float4*)&b[off + 512];
    *(uint2*)&xn[base + off] = (uint2){
        pk2(d0.x * rs * w0.x + b0.x, d0.y * rs * w0.y + b0.y),
        pk2(d0.z * rs * w0.z + b0.z, d0.w * rs * w0.w + b0.w)};
    *(uint2*)&xn[base + off + 256] = (uint2){
        pk2(d1.x * rs * w1.x + b1.x, d1.y * rs * w1.y + b1.y),
        pk2(d1.z * rs * w1.z + b1.z, d1.w * rs * w1.w + b1.w)};
    *(uint2*)&xn[base + off + 512] = (uint2){
        pk2(d2.x * rs * w2.x + b2.x, d2.y * rs * w2.y + b2.y),
        pk2(d2.z * rs * w2.z + b2.z, d2.w * rs * w2.w + b2.w)};
}

// ---------------- final LN: out = LN(xcur + res), wave-per-row --------------
__global__ __launch_bounds__(256) void final_ln_kernel(
    const float* __restrict__ xcur, const float* __restrict__ res,
    const float* __restrict__ w, const float* __restrict__ b,
    float* __restrict__ out) {
    int wave = threadIdx.x >> 6, lane = threadIdx.x & 63;
    int row = blockIdx.x * 4 + wave;
    size_t base = (size_t)row * D_;
    int off = lane * 4;
    float4 v0 = *(const float4*)&xcur[base + off];
    float4 v1 = *(const float4*)&xcur[base + off + 256];
    float4 v2 = *(const float4*)&xcur[base + off + 512];
    float4 r0 = *(const float4*)&res[base + off];
    float4 r1 = *(const float4*)&res[base + off + 256];
    float4 r2 = *(const float4*)&res[base + off + 512];
    v0.x += r0.x; v0.y += r0.y; v0.z += r0.z; v0.w += r0.w;
    v1.x += r1.x; v1.y += r1.y; v1.z += r1.z; v1.w += r1.w;
    v2.x += r2.x; v2.y += r2.y; v2.z += r2.z; v2.w += r2.w;
    float s = (v0.x + v0.y + v0.z + v0.w) + (v1.x + v1.y + v1.z + v1.w)
            + (v2.x + v2.y + v2.z + v2.w);
    float mu = wave_sum(s) * (1.0f / D_);
    float4 d0 = make_float4(v0.x - mu, v0.y - mu, v0.z - mu, v0.w - mu);
    float4 d1 = make_float4(v1.x - mu, v1.y - mu, v1.z - mu, v1.w - mu);
    float4 d2 = make_float4(v2.x - mu, v2.y - mu, v2.z - mu, v2.w - mu);
    float sv = d0.x * d0.x + d0.y * d0.y + d0.z * d0.z + d0.w * d0.w
             + d1.x * d1.x + d1.y * d1.y + d1.z * d1.z + d1.w * d1.w
             + d2.x * d2.x + d2.y * d2.y + d2.z * d2.z + d2.w * d2.w;
    float var = wave_sum(sv) * (1.0f / D_);
    float rs = rsqrtf(var + EPS_);
    float4 w0 = *(const float4*)&w[off];
    float4 w1 = *(const float4*)&w[off + 256];
    float4 w2 = *(const float4*)&w[off + 512];
    float4 b0 = *(const float4*)&b[off];
    float4 b1 = *(const float4*)&b[off + 256];
    float4 b2 = *(const float4*)&b[off + 512];
    *(float4*)&out[base + off] = make_float4(
        d0.x * rs * w0.x + b0.x, d0.y * rs * w0.y + b0.y,
        d0.z * rs * w0.z + b0.z, d0.w * rs * w0.w + b0.w);
    *(float4*)&out[base + off + 256] = make_float4(
        d1.x * rs * w1.x + b1.x, d1.y * rs * w1.y + b1.y,
        d1.z * rs * w1.z + b1.z, d1.w * rs * w1.w + b1.w);
    *(float4*)&out[base + off + 512] = make_float4(
        d2.x * rs * w2.x + b2.x, d2.y * rs * w2.y + b2.y,
        d2.z * rs * w2.z + b2.z, d2.w * rs * w2.w + b2.w);
}

// ---------------- bf16 MFMA GEMM: C[M,N] = A[M,K] * W[N,K]^T ---------------
// BK=64 tiles, XOR chunk swizzle: chunk slot s of row r holds original column
// chunk s^(r&7). Staging pre-swizzles the per-lane GLOBAL address (LDS dest
// stays linear per gload_lds constraint); reads apply the same XOR.
// Bank check: 16 lanes reading chunk c of rows r..r+15 hit 8 distinct 4-bank
// regions (2 lanes each) -> 2-way = conflict-free (was 8-way at BK=32).
template <int BM, int BN>
__global__ __launch_bounds__(256) void gemm_bf16_t(
    const unsigned short* __restrict__ A,   // M x K bf16 row-major
    const unsigned short* __restrict__ W,   // N x K bf16 row-major
    float* __restrict__ C, int M, int N, int K) {
    constexpr int FM = BM / 32;
    constexpr int FN = BN / 32;
    constexpr int NLD = (BM + BN) / 32;     // 16B chunks per thread per k-tile
    __shared__ unsigned short sA[BM * 64];
    __shared__ unsigned short sW[BN * 64];
    int bm = blockIdx.y * BM, bn = blockIdx.x * BN;
    int tid = threadIdx.x;
    int wave = tid >> 6, lane = tid & 63;
    int wrow = (wave & 1) * (BM / 2), wcol = (wave >> 1) * (BN / 2);
    int quad = lane >> 4, r16 = lane & 15;
    f32x4 acc[FM][FN];
    #pragma unroll
    for (int i = 0; i < FM; i++)
        #pragma unroll
        for (int j = 0; j < FN; j++)
            acc[i][j] = (f32x4){0.f, 0.f, 0.f, 0.f};

    for (int k0 = 0; k0 < K; k0 += 64) {
        #pragma unroll
        for (int r = 0; r < NLD; r++) {
            if (r < BM / 32) {            // A: BM*8 chunks
                int j = r * 256 + tid;
                int row = j >> 3, s = j & 7;
                gload16(&A[(size_t)(bm + row) * K + k0 + ((s ^ (row & 7)) * 8)],
                        &sA[(r * 256 + wave * 64) * 8]);
            } else {                      // W: BN*8 chunks
                int j = (r - BM / 32) * 256 + tid;
                int row = j >> 3, s = j & 7;
                gload16(&W[(size_t)(bn + row) * K + k0 + ((s ^ (row & 7)) * 8)],
                        &sW[((r - BM / 32) * 256 + wave * 64) * 8]);
            }
        }
        __syncthreads();
        #pragma unroll
        for (int kk = 0; kk < 2; kk++) {
            bf16x8 af[FM], wf[FN];
            #pragma unroll
            for (int i = 0; i < FM; i++) {
                int row = wrow + i * 16 + r16;
                af[i] = *(const bf16x8*)&sA[row * 64 + (((kk * 4 + quad) ^ (row & 7)) * 8)];
            }
            #pragma unroll
            for (int j = 0; j < FN; j++) {
                int row = wcol + j * 16 + r16;
                wf[j] = *(const bf16x8*)&sW[row * 64 + (((kk * 4 + quad) ^ (row & 7)) * 8)];
            }
            #pragma unroll
            for (int i = 0; i < FM; i++)
                #pragma unroll
                for (int j = 0; j < FN; j++)
                    acc[i][j] = __builtin_amdgcn_mfma_f32_16x16x32_bf16(
                        af[i], wf[j], acc[i][j], 0, 0, 0);
        }
        __syncthreads();
    }
    #pragma unroll
    for (int i = 0; i < FM; i++) {
        #pragma unroll
        for (int j = 0; j < FN; j++) {
            int col = bn + wcol + j * 16 + r16;
            #pragma unroll
            for (int reg = 0; reg < 4; reg++) {
                int row = bm + wrow + i * 16 + quad * 4 + reg;
                C[(size_t)row * N + col] = acc[i][j][reg];
            }
        }
    }
}

// ---------------- dt GEMM bf16 MFMA (M=2048, N=DI, K=64) --------------------
// Single BK=64 step with the same XOR chunk swizzle; softplus epilogue.
__global__ __launch_bounds__(256) void dt_gemm_bf16(
    const unsigned short* __restrict__ A,   // M x 64 (dbc_bf, cols 48+ = 0)
    const unsigned short* __restrict__ W,   // DI x 64 (wdt_bf layer)
    const float* __restrict__ bias,
    float* __restrict__ dtb) {
    __shared__ unsigned short sA[128 * 64];
    __shared__ unsigned short sW[128 * 64];
    int bm = blockIdx.y * 128, bn = blockIdx.x * 128;
    int tid = threadIdx.x;
    int wave = tid >> 6, lane = tid & 63;
    int wrow = (wave & 1) * 64, wcol = (wave >> 1) * 64;
    int quad = lane >> 4, r16 = lane & 15;
    f32x4 acc[4][4];
    #pragma unroll
    for (int i = 0; i < 4; i++)
        #pragma unroll
        for (int j = 0; j < 4; j++)
            acc[i][j] = (f32x4){0.f, 0.f, 0.f, 0.f};

    #pragma unroll
    for (int r = 0; r < 8; r++) {
        if (r < 4) {
            int j = r * 256 + tid;
            int row = j >> 3, s = j & 7;
            gload16(&A[(size_t)(bm + row) * KDT_ + ((s ^ (row & 7)) * 8)],
                    &sA[(r * 256 + wave * 64) * 8]);
        } else {
            int j = (r - 4) * 256 + tid;
            int row = j >> 3, s = j & 7;
            gload16(&W[(size_t)(bn + row) * KDT_ + ((s ^ (row & 7)) * 8)],
                    &sW[((r - 4) * 256 + wave * 64) * 8]);
        }
    }
    __syncthreads();
    #pragma unroll
    for (int kk = 0; kk < 2; kk++) {
        bf16x8 af[4], wf[4];
        #pragma unroll
        for (int i = 0; i < 4; i++) {
            int row = wrow + i * 16 + r16;
            af[i] = *(const bf16x8*)&sA[row * 64 + (((kk * 4 + quad) ^ (row & 7)) * 8)];
        }
        #pragma unroll
        for (int j = 0; j < 4; j++) {
            int row = wcol + j * 16 + r16;
            wf[j] = *(const bf16x8*)&sW[row * 64 + (((kk * 4 + quad) ^ (row & 7)) * 8)];
        }
        #pragma unroll
        for (int i = 0; i < 4; i++)
            #pragma unroll
            for (int j = 0; j < 4; j++)
                acc[i][j] = __builtin_amdgcn_mfma_f32_16x16x32_bf16(
                    af[i], wf[j], acc[i][j], 0, 0, 0);
    }
    #pragma unroll
    for (int i = 0; i < 4; i++) {
        #pragma unroll
        for (int j = 0; j < 4; j++) {
            int col = bn + wcol + j * 16 + r16;
            float bv = bias[col];
            #pragma unroll
            for (int reg = 0; reg < 4; reg++) {
                int row = bm + wrow + i * 16 + quad * 4 + reg;
                float v = acc[i][j][reg] + bv;
                v = (v > 20.f) ? v : log1pf(__expf(v));
                dtb[(size_t)row * DI_ + col] = v;
            }
        }
    }
}

// ---------------- fused conv+SiLU+x_proj GEMM (split-K over ks) -------------
__global__ __launch_bounds__(256) void conv_xproj_kernel(
    const float* __restrict__ xz,
    const float* __restrict__ cw,
    const float* __restrict__ cb,
    const unsigned short* __restrict__ W,
    float* __restrict__ xcf,
    float* __restrict__ Pb) {
    __shared__ float sxz[67 * 96];
    __shared__ unsigned short sxcb[64 * 104];
    __shared__ float scw[96 * 4];
    __shared__ float scb[96];
    unsigned short* sW = (unsigned short*)sxz;

    int ks = blockIdx.x;
    int bm = blockIdx.y * 64;
    int tid = threadIdx.x;
    int b = bm >> 10, t0 = bm & (L_ - 1);
    int dbase = ks * KCH_;

    if (tid < 96) {
        int d = dbase + tid;
        *(float4*)&scw[tid * 4] = *(const float4*)&cw[d * 4];
        scb[tid] = cb[d];
    }
    for (int j = tid; j < 67 * 24; j += 256) {
        int r = j / 24, c4 = (j % 24) * 4;
        int tt = t0 + r - 3;
        float4 v = make_float4(0.f, 0.f, 0.f, 0.f);
        if (tt >= 0)
            v = *(const float4*)&xz[((size_t)(b * L_ + tt)) * (2 * DI_) + dbase + c4];
        *(float4*)&sxz[r * 96 + c4] = v;
    }
    __syncthreads();
    for (int j = tid; j < 64 * 96; j += 256) {
        int r = j / 96, c = j % 96;
        float acc = scb[c];
        #pragma unroll
        for (int k = 0; k < KC_; k++)
            acc = fmaf(scw[c * 4 + k], sxz[(r + k) * 96 + c], acc);
        float v = acc / (1.0f + __expf(-acc));
        xcf[(size_t)(bm + r) * DI_ + dbase + c] = v;
        sxcb[r * 104 + c] = f2bf(v);
    }
    __syncthreads();
    for (int j = tid; j < 80 * 12; j += 256) {
        int row = j / 12, c16 = (j % 12) * 8;
        *(uint4*)&sW[row * 104 + c16] =
            *(const uint4*)&W[(size_t)row * DI_ + dbase + c16];
    }
    __syncthreads();
    int wave = tid >> 6, lane = tid & 63;
    int quad = lane >> 4, r16 = lane & 15;
    f32x4 acc[5];
    #pragma unroll
    for (int j = 0; j < 5; j++) acc[j] = (f32x4){0.f, 0.f, 0.f, 0.f};
    #pragma unroll
    for (int kk = 0; kk < 3; kk++) {
        bf16x8 af = *(const bf16x8*)&sxcb[(wave * 16 + r16) * 104 + kk * 32 + quad * 8];
        #pragma unroll
        for (int j = 0; j < 5; j++) {
            bf16x8 wf = *(const bf16x8*)&sW[(j * 16 + r16) * 104 + kk * 32 + quad * 8];
            acc[j] = __builtin_amdgcn_mfma_f32_16x16x32_bf16(af, wf, acc[j], 0, 0, 0);
        }
    }
    #pragma unroll
    for (int j = 0; j < 5; j++) {
        int col = j * 16 + r16;
        #pragma unroll
        for (int reg = 0; reg < 4; reg++) {
            int row = bm + wave * 16 + quad * 4 + reg;
            Pb[((size_t)ks * M_ + row) * 80 + col] = acc[j][reg];
        }
    }
}

// reduce split-K partials; scatter into dbc_bf (M x 64 bf16) and packed BC
__global__ void xproj_reduce_kernel(const float* __restrict__ Pb,
                                    unsigned short* __restrict__ dbc_bf,
                                    float* __restrict__ bcp) {
    int i = blockIdx.x * 256 + threadIdx.x;   // over M_*80
    float s = 0.f;
    #pragma unroll
    for (int ks = 0; ks < KS_; ks++) s += Pb[(size_t)ks * (M_ * 80) + i];
    int m = i / 80, col = i % 80;
    if (col < DR_) {
        dbc_bf[m * KDT_ + col] = f2bf(s);
    } else if (col < DR_ + NS_) {
        bcp[m * 32 + 2 * (col - DR_)] = s;         // B_n
    } else {
        bcp[m * 32 + 2 * (col - DR_ - NS_) + 1] = s; // C_n
    }
}

// ---------------- scan pass A: per-chunk summaries (S[16] + sd scalar) ------
__global__ __launch_bounds__(128) void scan_ps_kernel(
    const float* __restrict__ dtb,
    const float* __restrict__ xcf,
    const float4* __restrict__ bcp4,
    const float* __restrict__ negA,
    float* __restrict__ Sb,
    float* __restrict__ sdb) {
    const int NDB = DI_ / 128;         // 12 d-blocks
    int bx = blockIdx.x;
    int dblk = bx % NDB;
    int c = (bx / NDB) % NC_;
    int b = bx / (NDB * NC_);
    int d = dblk * 128 + threadIdx.x;

    float A[NS_];
    #pragma unroll
    for (int n = 0; n < NS_; n++) A[n] = negA[(size_t)d * NS_ + n];
    float h[NS_];
    #pragma unroll
    for (int n = 0; n < NS_; n++) h[n] = 0.f;
    float sd = 0.f;

    size_t btbase = (size_t)(b * L_ + c * T_);
    const float* pdt = dtb + btbase * DI_ + d;
    const float* pxc = xcf + btbase * DI_ + d;
    const float4* pbc = bcp4 + btbase * 8;

    #pragma unroll 4
    for (int t = 0; t < T_; t++) {
        float dt = pdt[(size_t)t * DI_];
        float u  = dt * pxc[(size_t)t * DI_];
        sd += dt;
        #pragma unroll
        for (int q = 0; q < 8; q++) {
            float4 v = pbc[t * 8 + q];
            float e0 = __expf(dt * A[2 * q]);
            h[2 * q] = fmaf(e0, h[2 * q], u * v.x);
            float e1 = __expf(dt * A[2 * q + 1]);
            h[2 * q + 1] = fmaf(e1, h[2 * q + 1], u * v.z);
        }
    }

    size_t o = (((size_t)b * NC_ + c) * DI_ + d) * NS_;
    #pragma unroll
    for (int n = 0; n < NS_; n++) Sb[o + n] = h[n];
    sdb[((size_t)b * NC_ + c) * DI_ + d] = sd;
}

// ---------------- scan pass B: sequential combine, 4-deep pipeline ----------
__global__ __launch_bounds__(64) void scan_combine_kernel(
    const float* __restrict__ Sb, const float* __restrict__ sdb,
    const float* __restrict__ negA, float* __restrict__ hin) {
    int i = blockIdx.x * 64 + threadIdx.x;    // over B*DI*NS
    int b = i / (DI_ * NS_);
    int rem = i % (DI_ * NS_);
    int d = rem >> 4;                          // NS = 16
    float Aa = negA[rem];
    const size_t str = (size_t)DI_ * NS_;
    size_t o = (size_t)b * NC_ * str + rem;
    size_t osd = (size_t)b * NC_ * DI_ + d;
    float h = 0.f;
    float s0 = Sb[o],           sd0 = sdb[osd];
    float s1 = Sb[o + str],     sd1 = sdb[osd + DI_];
    float s2 = Sb[o + 2 * str], sd2 = sdb[osd + 2 * DI_];
    float s3 = Sb[o + 3 * str], sd3 = sdb[osd + 3 * DI_];
    for (int c = 0; c < NC_ - 4; c += 4) {
        float n0 = Sb[o + 4 * str], nd0 = sdb[osd + 4 * DI_];
        float n1 = Sb[o + 5 * str], nd1 = sdb[osd + 5 * DI_];
        float n2 = Sb[o + 6 * str], nd2 = sdb[osd + 6 * DI_];
        float n3 = Sb[o + 7 * str], nd3 = sdb[osd + 7 * DI_];
        hin[o] = h;           h = fmaf(__expf(Aa * sd0), h, s0);
        hin[o + str] = h;     h = fmaf(__expf(Aa * sd1), h, s1);
        hin[o + 2 * str] = h; h = fmaf(__expf(Aa * sd2), h, s2);
        hin[o + 3 * str] = h; h = fmaf(__expf(Aa * sd3), h, s3);
        s0 = n0; sd0 = nd0; s1 = n1; sd1 = nd1;
        s2 = n2; sd2 = nd2; s3 = n3; sd3 = nd3;
        o += 4 * str; osd += 4 * DI_;
    }
    hin[o] = h;           h = fmaf(__expf(Aa * sd0), h, s0);
    hin[o + str] = h;     h = fmaf(__expf(Aa * sd1), h, s1);
    hin[o + 2 * str] = h; h = fmaf(__expf(Aa * sd2), h, s2);
    hin[o + 3 * str] = h;
}

// ---------------- scan pass C: exact recurrence from hin -> yg --------------
__global__ __launch_bounds__(128) void scan_out_kernel(
    const float* __restrict__ dtb, const float* __restrict__ xcf,
    const float4* __restrict__ bcp4, const float* __restrict__ negA,
    const float* __restrict__ hin, const float* __restrict__ xz,
    const float* __restrict__ Dp, unsigned short* __restrict__ yg) {
    const int NDB = DI_ / 128;
    int bx = blockIdx.x;
    int dblk = bx % NDB;
    int c = (bx / NDB) % NC_;
    int b = bx / (NDB * NC_);
    int d = dblk * 128 + threadIdx.x;

    float A[NS_];
    #pragma unroll
    for (int n = 0; n < NS_; n++) A[n] = negA[(size_t)d * NS_ + n];
    size_t o = (((size_t)b * NC_ + c) * DI_ + d) * NS_;
    float h[NS_];
    #pragma unroll
    for (int n = 0; n < NS_; n++) h[n] = hin[o + n];
    float dpv = Dp[d];

    size_t btbase = (size_t)(b * L_ + c * T_);
    const float* pdt = dtb + btbase * DI_ + d;
    const float* pxc = xcf + btbase * DI_ + d;
    const float4* pbc = bcp4 + btbase * 8;

    #pragma unroll 4
    for (int t = 0; t < T_; t++) {
        float dt = pdt[(size_t)t * DI_];
        float xc = pxc[(size_t)t * DI_];
        float u = dt * xc;
        float y = 0.f;
        #pragma unroll
        for (int q = 0; q < 8; q++) {
            float4 v = pbc[t * 8 + q];
            float e0 = __expf(dt * A[2 * q]);
            h[2 * q] = fmaf(e0, h[2 * q], u * v.x);
            y = fmaf(v.y, h[2 * q], y);
            float e1 = __expf(dt * A[2 * q + 1]);
            h[2 * q + 1] = fmaf(e1, h[2 * q + 1], u * v.z);
            y = fmaf(v.w, h[2 * q + 1], y);
        }
        size_t row = btbase + t;
        float zv = xz[row * (2 * DI_) + DI_ + d];
        float yy = y + xc * dpv;
        yy *= zv / (1.0f + __expf(-zv));
        yg[row * DI_ + d] = f2bf(yy);
    }
}

extern "C" void kernel_launch(void* const* d_in, const int* in_sizes, int n_in,
                              void* d_out, int out_size, void* d_ws, size_t ws_size,
                              hipStream_t stream) {
    const float* x        = (const float*)d_in[0];
    const float* ln_w     = (const float*)d_in[1];
    const float* ln_b     = (const float*)d_in[2];
    const float* in_proj  = (const float*)d_in[3];
    const float* conv_w   = (const float*)d_in[4];
    const float* conv_b   = (const float*)d_in[5];
    const float* x_proj   = (const float*)d_in[6];
    const float* dt_w     = (const float*)d_in[7];
    const float* dt_b     = (const float*)d_in[8];
    const float* A_log    = (const float*)d_in[9];
    const float* D_skip   = (const float*)d_in[10];
    const float* out_proj = (const float*)d_in[11];
    const float* fn_w     = (const float*)d_in[12];
    const float* fn_b     = (const float*)d_in[13];
    float* out = (float*)d_out;

    char* p = (char*)d_ws;
    auto alloc = [&](size_t bytes) {
        char* r = p;
        p += (bytes + 255) & ~(size_t)255;
        return (void*)r;
    };
    float* xcur = (float*)alloc((size_t)M_ * D_ * 4);
    float* res  = (float*)alloc((size_t)M_ * D_ * 4);
    unsigned short* xn = (unsigned short*)alloc((size_t)M_ * D_ * 2);
    float* xz   = (float*)alloc((size_t)M_ * 2 * DI_ * 4);
    float* dtb  = (float*)alloc((size_t)M_ * DI_ * 4);
    float* xcf  = (float*)alloc((size_t)M_ * DI_ * 4);
    unsigned short* dbc_bf = (unsigned short*)alloc((size_t)M_ * KDT_ * 2);
    float* bcp  = (float*)alloc((size_t)M_ * 32 * 4);
    unsigned short* yg = (unsigned short*)alloc((size_t)M_ * DI_ * 2);
    float* Sb   = (float*)alloc((size_t)B_ * NC_ * DI_ * NS_ * 4);   // 6.3 MB
    float* sdb  = (float*)alloc((size_t)B_ * NC_ * DI_ * 4);         // 0.4 MB
    float* hin  = (float*)alloc((size_t)B_ * NC_ * DI_ * NS_ * 4);
    float* Pb   = (float*)alloc((size_t)KS_ * M_ * 80 * 4);
    float* negA = (float*)alloc((size_t)NL_ * DI_ * NS_ * 4);
    const size_t n_wi = (size_t)NL_ * 2 * DI_ * D_;
    const size_t n_wo = (size_t)NL_ * D_ * DI_;
    const size_t n_wx = (size_t)NL_ * 80 * DI_;
    const size_t n_wdt = (size_t)NL_ * DI_ * KDT_;
    unsigned short* wi_bf = (unsigned short*)alloc(n_wi * 2);
    unsigned short* wo_bf = (unsigned short*)alloc(n_wo * 2);
    unsigned short* wx_bf = (unsigned short*)alloc(n_wx * 2);
    unsigned short* wdt_bf = (unsigned short*)alloc(n_wdt * 2);

    prep_kernel<<<7808, 256, 0, stream>>>(
        in_proj, wi_bf, out_proj, wo_bf, x_proj, wx_bf,
        dt_w, wdt_bf, A_log, negA, x, xcur, res, dbc_bf);

    for (int l = 0; l < NL_; l++) {
        const float* negA_l = negA + (size_t)l * DI_ * NS_;

        ln_res_kernel<<<M_ / 4, 256, 0, stream>>>(
            xcur, res, ln_w + l * D_, ln_b + l * D_, xn);

        // xz = xn @ Wi^T  (M=2048, N=3072, K=768): 128x64 -> 768 blocks (3/CU)
        gemm_bf16_t<128, 64><<<dim3((2 * DI_) / 64, M_ / 128), 256, 0, stream>>>(
            xn, wi_bf + (size_t)l * 2 * DI_ * D_, xz, M_, 2 * DI_, D_);

        conv_xproj_kernel<<<dim3(KS_, M_ / 64), 256, 0, stream>>>(
            xz, conv_w + l * DI_ * KC_, conv_b + l * DI_,
            wx_bf + (size_t)l * 80 * DI_, xcf, Pb);
        xproj_reduce_kernel<<<(M_ * 80) / 256, 256, 0, stream>>>(Pb, dbc_bf, bcp);

        dt_gemm_bf16<<<dim3(DI_ / 128, M_ / 128), 256, 0, stream>>>(
            dbc_bf, wdt_bf + (size_t)l * DI_ * KDT_, dt_b + l * DI_, dtb);

        scan_ps_kernel<<<B_ * NC_ * (DI_ / 128), 128, 0, stream>>>(
            dtb, xcf, (const float4*)bcp, negA_l, Sb, sdb);
        scan_combine_kernel<<<(B_ * DI_ * NS_) / 64, 64, 0, stream>>>(
            Sb, sdb, negA_l, hin);
        scan_out_kernel<<<B_ * NC_ * (DI_ / 128), 128, 0, stream>>>(
            dtb, xcf, (const float4*)bcp, negA_l, hin, xz,
            D_skip + (size_t)l * DI_, yg);

        // xcur = yg @ Wo^T  (M=2048, N=768, K=1536): 64x64 -> 384 blocks
        gemm_bf16_t<64, 64><<<dim3(D_ / 64, M_ / 64), 256, 0, stream>>>(
            yg, wo_bf + (size_t)l * D_ * DI_, xcur, M_, D_, DI_);
    }

    final_ln_kernel<<<M_ / 4, 256, 0, stream>>>(xcur, res, fn_w, fn_b, out);
}

// Round 11
// 1180.063 us; speedup vs baseline: 2.2959x; 1.0090x over previous
//
#include <hip/hip_runtime.h>
#include <math.h>

#define B_ 2
#define L_ 1024
#define D_ 768
#define NL_ 8
#define DI_ 1536
#define NS_ 16
#define DR_ 48
#define KC_ 4
#define EPS_ 1e-5f
#define M_ (B_*L_)   // 2048 rows
#define NC_ 32       // scan chunks
#define T_ 32        // chunk length (NC_*T_ == L_)
#define KS_ 16       // x_proj split-K factor
#define KCH_ (DI_/KS_)   // 96 per split
#define KDT_ 64          // dt GEMM padded K (48 -> 64)

typedef short bf16x8 __attribute__((ext_vector_type(8)));
typedef float f32x4  __attribute__((ext_vector_type(4)));

// ---------------- fp32 -> bf16 (RNE) ---------------------------------------
__device__ __forceinline__ unsigned short f2bf(float f) {
    union { float f; unsigned int u; } v; v.f = f;
    unsigned int u = v.u;
    u += 0x7fffu + ((u >> 16) & 1u);
    return (unsigned short)(u >> 16);
}

__device__ __forceinline__ unsigned int pk2(float a, float b) {
    union { float f; unsigned int u; } va, vb;
    va.f = a; vb.f = b;
    unsigned int ua = va.u + (0x7fffu + ((va.u >> 16) & 1u));
    unsigned int ub = vb.u + (0x7fffu + ((vb.u >> 16) & 1u));
    return (ua >> 16) | (ub & 0xffff0000u);
}

// async global->LDS, 16B per lane; LDS dest must be wave-uniform base + lane*16
// NOTE: only call with FULL exec mask (divergence breaks the uniform-base rule).
__device__ __forceinline__ void gload16(const void* g, void* l) {
    __builtin_amdgcn_global_load_lds(
        (const __attribute__((address_space(1))) void*)g,
        (__attribute__((address_space(3))) void*)l, 16, 0, 0);
}

// ---------------- prep (clock-ramp-bound; structure frozen) -----------------
__device__ __forceinline__ void cvt_blk(const float* __restrict__ s,
                                        unsigned short* __restrict__ d, int tid) {
    int o = tid * 4;
    float4 a0 = *(const float4*)&s[o];
    float4 a1 = *(const float4*)&s[o + 1024];
    float4 a2 = *(const float4*)&s[o + 2048];
    float4 a3 = *(const float4*)&s[o + 3072];
    *(uint2*)&d[o]        = (uint2){pk2(a0.x, a0.y), pk2(a0.z, a0.w)};
    *(uint2*)&d[o + 1024] = (uint2){pk2(a1.x, a1.y), pk2(a1.z, a1.w)};
    *(uint2*)&d[o + 2048] = (uint2){pk2(a2.x, a2.y), pk2(a2.z, a2.w)};
    *(uint2*)&d[o + 3072] = (uint2){pk2(a3.x, a3.y), pk2(a3.z, a3.w)};
}

__global__ __launch_bounds__(256) void prep_kernel(
    const float* __restrict__ wi, unsigned short* __restrict__ wi_bf,
    const float* __restrict__ wo, unsigned short* __restrict__ wo_bf,
    const float* __restrict__ wx, unsigned short* __restrict__ wx_bf,
    const float* __restrict__ wdt, unsigned short* __restrict__ wdt_bf,
    const float* __restrict__ A_log, float* __restrict__ negA,
    const float* __restrict__ x, float* __restrict__ xcur,
    float* __restrict__ res,
    unsigned short* __restrict__ dbc_bf) {
    const int E0 = NL_ * 2 * DI_ * D_;   // 18874368 wi
    const int E1 = NL_ * D_ * DI_;       // 9437184  wo
    const int E2 = NL_ * 80 * DI_;       // 983040   wx
    const int E3 = NL_ * DI_ * KDT_;     // 786432   wdt
    const int E4 = NL_ * DI_ * NS_;      // 196608   negA
    const int E5 = M_ * D_;              // 1572864  init
    int tid = threadIdx.x;
    int base = blockIdx.x * 4096;
    if (base < E0) { cvt_blk(wi + base, wi_bf + base, tid); return; }
    base -= E0;
    if (base < E1) { cvt_blk(wo + base, wo_bf + base, tid); return; }
    base -= E1;
    if (base < E2) { cvt_blk(wx + base, wx_bf + base, tid); return; }
    base -= E2;
    if (base < E3) {                     // dt_w: K padded 48 -> 64
        int off0 = base + tid * 4;
        int col = off0 & (KDT_ - 1);
        if (col < DR_) {
            float4 a0 = *(const float4*)&wdt[(size_t)((off0) >> 6) * DR_ + col];
            float4 a1 = *(const float4*)&wdt[(size_t)((off0 + 1024) >> 6) * DR_ + col];
            float4 a2 = *(const float4*)&wdt[(size_t)((off0 + 2048) >> 6) * DR_ + col];
            float4 a3 = *(const float4*)&wdt[(size_t)((off0 + 3072) >> 6) * DR_ + col];
            *(uint2*)&wdt_bf[off0]        = (uint2){pk2(a0.x, a0.y), pk2(a0.z, a0.w)};
            *(uint2*)&wdt_bf[off0 + 1024] = (uint2){pk2(a1.x, a1.y), pk2(a1.z, a1.w)};
            *(uint2*)&wdt_bf[off0 + 2048] = (uint2){pk2(a2.x, a2.y), pk2(a2.z, a2.w)};
            *(uint2*)&wdt_bf[off0 + 3072] = (uint2){pk2(a3.x, a3.y), pk2(a3.z, a3.w)};
        } else {
            uint2 z = {0u, 0u};
            *(uint2*)&wdt_bf[off0] = z;
            *(uint2*)&wdt_bf[off0 + 1024] = z;
            *(uint2*)&wdt_bf[off0 + 2048] = z;
            *(uint2*)&wdt_bf[off0 + 3072] = z;
        }
        return;
    }
    base -= E3;
    if (base < E4) {                     // negA = -exp(A_log)
        int off0 = base + tid * 4;
        float4 a0 = *(const float4*)&A_log[off0];
        float4 a1 = *(const float4*)&A_log[off0 + 1024];
        float4 a2 = *(const float4*)&A_log[off0 + 2048];
        float4 a3 = *(const float4*)&A_log[off0 + 3072];
        *(float4*)&negA[off0] = make_float4(-__expf(a0.x), -__expf(a0.y), -__expf(a0.z), -__expf(a0.w));
        *(float4*)&negA[off0 + 1024] = make_float4(-__expf(a1.x), -__expf(a1.y), -__expf(a1.z), -__expf(a1.w));
        *(float4*)&negA[off0 + 2048] = make_float4(-__expf(a2.x), -__expf(a2.y), -__expf(a2.z), -__expf(a2.w));
        *(float4*)&negA[off0 + 3072] = make_float4(-__expf(a3.x), -__expf(a3.y), -__expf(a3.z), -__expf(a3.w));
        return;
    }
    base -= E4;
    if (base < E5) {                     // xcur = x; res = 0
        int off0 = base + tid * 4;
        float4 a0 = *(const float4*)&x[off0];
        float4 a1 = *(const float4*)&x[off0 + 1024];
        float4 a2 = *(const float4*)&x[off0 + 2048];
        float4 a3 = *(const float4*)&x[off0 + 3072];
        float4 z = make_float4(0.f, 0.f, 0.f, 0.f);
        *(float4*)&xcur[off0] = a0;        *(float4*)&res[off0] = z;
        *(float4*)&xcur[off0 + 1024] = a1; *(float4*)&res[off0 + 1024] = z;
        *(float4*)&xcur[off0 + 2048] = a2; *(float4*)&res[off0 + 2048] = z;
        *(float4*)&xcur[off0 + 3072] = a3; *(float4*)&res[off0 + 3072] = z;
        return;
    }
    base -= E5;
    {                                    // zero dbc_bf pad (cols >= 48 stay 0)
        int off0 = base + tid * 4;
        uint2 z = {0u, 0u};
        *(uint2*)&dbc_bf[off0] = z;
        *(uint2*)&dbc_bf[off0 + 1024] = z;
        *(uint2*)&dbc_bf[off0 + 2048] = z;
        *(uint2*)&dbc_bf[off0 + 3072] = z;
    }
}

// ---------------- wave-wide sum (64 lanes), result broadcast ----------------
__device__ __forceinline__ float wave_sum(float v) {
    #pragma unroll
    for (int o = 32; o > 0; o >>= 1) v += __shfl_down(v, o);
    return __shfl(v, 0);
}

// ---------------- fused residual-accumulate + LayerNorm (bf16 out) ----------
__global__ __launch_bounds__(256) void ln_res_kernel(
    const float* __restrict__ xcur, float* __restrict__ res,
    const float* __restrict__ w, const float* __restrict__ b,
    unsigned short* __restrict__ xn) {
    int wave = threadIdx.x >> 6, lane = threadIdx.x & 63;
    int row = blockIdx.x * 4 + wave;
    size_t base = (size_t)row * D_;
    int off = lane * 4;
    float4 v0 = *(const float4*)&xcur[base + off];
    float4 v1 = *(const float4*)&xcur[base + off + 256];
    float4 v2 = *(const float4*)&xcur[base + off + 512];
    float4 r0 = *(const float4*)&res[base + off];
    float4 r1 = *(const float4*)&res[base + off + 256];
    float4 r2 = *(const float4*)&res[base + off + 512];
    r0.x += v0.x; r0.y += v0.y; r0.z += v0.z; r0.w += v0.w;
    r1.x += v1.x; r1.y += v1.y; r1.z += v1.z; r1.w += v1.w;
    r2.x += v2.x; r2.y += v2.y; r2.z += v2.z; r2.w += v2.w;
    *(float4*)&res[base + off]       = r0;
    *(float4*)&res[base + off + 256] = r1;
    *(float4*)&res[base + off + 512] = r2;
    float s = (v0.x + v0.y + v0.z + v0.w) + (v1.x + v1.y + v1.z + v1.w)
            + (v2.x + v2.y + v2.z + v2.w);
    float mu = wave_sum(s) * (1.0f / D_);
    float4 d0 = make_float4(v0.x - mu, v0.y - mu, v0.z - mu, v0.w - mu);
    float4 d1 = make_float4(v1.x - mu, v1.y - mu, v1.z - mu, v1.w - mu);
    float4 d2 = make_float4(v2.x - mu, v2.y - mu, v2.z - mu, v2.w - mu);
    float sv = d0.x * d0.x + d0.y * d0.y + d0.z * d0.z + d0.w * d0.w
             + d1.x * d1.x + d1.y * d1.y + d1.z * d1.z + d1.w * d1.w
             + d2.x * d2.x + d2.y * d2.y + d2.z * d2.z + d2.w * d2.w;
    float var = wave_sum(sv) * (1.0f / D_);
    float rs = rsqrtf(var + EPS_);
    float4 w0 = *(const float4*)&w[off];
    float4 w1 = *(const float4*)&w[off + 256];
    float4 w2 = *(const float4*)&w[off + 512];
    float4 b0 = *(const float4*)&b[off];
    float4 b1 = *(const float4*)&b[off + 256];
    float4 b2 = *(const float4*)&b[off + 512];
    *(uint2*)&xn[base + off] = (uint2){
        pk2(d0.x * rs * w0.x + b0.x, d0.y * rs * w0.y + b0.y),
        pk2(d0.z * rs * w0.z + b0.z, d0.w * rs * w0.w + b0.w)};
    *(uint2*)&xn[base + off + 256] = (uint2){
        pk2(d1.x * rs * w1.x + b1.x, d1.y * rs * w1.y + b1.y),
        pk2(d1.z * rs * w1.z + b1.z, d1.w * rs * w1.w + b1.w)};
    *(uint2*)&xn[base + off + 512] = (uint2){
        pk2(d2.x * rs * w2.x + b2.x, d2.y * rs * w2.y + b2.y),
        pk2(d2.z * rs * w2.z + b2.z, d2.w * rs * w2.w + b2.w)};
}

// ---------------- final LN: out = LN(xcur + res), wave-per-row --------------
__global__ __launch_bounds__(256) void final_ln_kernel(
    const float* __restrict__ xcur, const float* __restrict__ res,
    const float* __restrict__ w, const float* __restrict__ b,
    float* __restrict__ out) {
    int wave = threadIdx.x >> 6, lane = threadIdx.x & 63;
    int row = blockIdx.x * 4 + wave;
    size_t base = (size_t)row * D_;
    int off = lane * 4;
    float4 v0 = *(const float4*)&xcur[base + off];
    float4 v1 = *(const float4*)&xcur[base + off + 256];
    float4 v2 = *(const float4*)&xcur[base + off + 512];
    float4 r0 = *(const float4*)&res[base + off];
    float4 r1 = *(const float4*)&res[base + off + 256];
    float4 r2 = *(const float4*)&res[base + off + 512];
    v0.x += r0.x; v0.y += r0.y; v0.z += r0.z; v0.w += r0.w;
    v1.x += r1.x; v1.y += r1.y; v1.z += r1.z; v1.w += r1.w;
    v2.x += r2.x; v2.y += r2.y; v2.z += r2.z; v2.w += r2.w;
    float s = (v0.x + v0.y + v0.z + v0.w) + (v1.x + v1.y + v1.z + v1.w)
            + (v2.x + v2.y + v2.z + v2.w);
    float mu = wave_sum(s) * (1.0f / D_);
    float4 d0 = make_float4(v0.x - mu, v0.y - mu, v0.z - mu, v0.w - mu);
    float4 d1 = make_float4(v1.x - mu, v1.y - mu, v1.z - mu, v1.w - mu);
    float4 d2 = make_float4(v2.x - mu, v2.y - mu, v2.z - mu, v2.w - mu);
    float sv = d0.x * d0.x + d0.y * d0.y + d0.z * d0.z + d0.w * d0.w
             + d1.x * d1.x + d1.y * d1.y + d1.z * d1.z + d1.w * d1.w
             + d2.x * d2.x + d2.y * d2.y + d2.z * d2.z + d2.w * d2.w;
    float var = wave_sum(sv) * (1.0f / D_);
    float rs = rsqrtf(var + EPS_);
    float4 w0 = *(const float4*)&w[off];
    float4 w1 = *(const float4*)&w[off + 256];
    float4 w2 = *(const float4*)&w[off + 512];
    float4 b0 = *(const float4*)&b[off];
    float4 b1 = *(const float4*)&b[off + 256];
    float4 b2 = *(const float4*)&b[off + 512];
    *(float4*)&out[base + off] = make_float4(
        d0.x * rs * w0.x + b0.x, d0.y * rs * w0.y + b0.y,
        d0.z * rs * w0.z + b0.z, d0.w * rs * w0.w + b0.w);
    *(float4*)&out[base + off + 256] = make_float4(
        d1.x * rs * w1.x + b1.x, d1.y * rs * w1.y + b1.y,
        d1.z * rs * w1.z + b1.z, d1.w * rs * w1.w + b1.w);
    *(float4*)&out[base + off + 512] = make_float4(
        d2.x * rs * w2.x + b2.x, d2.y * rs * w2.y + b2.y,
        d2.z * rs * w2.z + b2.z, d2.w * rs * w2.w + b2.w);
}

// ---------------- bf16 MFMA GEMM: C[M,N] = A[M,K] * W[N,K]^T ---------------
// BK=64 + XOR chunk swizzle + double-buffered single-barrier pipeline
// (stage() always runs with FULL exec mask — gload16 constraint holds).
template <int BM, int BN>
__global__ __launch_bounds__(256) void gemm_bf16_t(
    const unsigned short* __restrict__ A,   // M x K bf16 row-major
    const unsigned short* __restrict__ W,   // N x K bf16 row-major
    float* __restrict__ C, int M, int N, int K) {
    constexpr int FM = BM / 32;
    constexpr int FN = BN / 32;
    constexpr int NLDA = BM / 32;
    constexpr int NLDW = BN / 32;
    __shared__ unsigned short sA[2][BM * 64];
    __shared__ unsigned short sW[2][BN * 64];
    int bm = blockIdx.y * BM, bn = blockIdx.x * BN;
    int tid = threadIdx.x;
    int wave = tid >> 6, lane = tid & 63;
    int wrow = (wave & 1) * (BM / 2), wcol = (wave >> 1) * (BN / 2);
    int quad = lane >> 4, r16 = lane & 15;

    auto stage = [&](int buf, int k0) {
        #pragma unroll
        for (int r = 0; r < NLDA; r++) {
            int j = r * 256 + tid;
            int row = j >> 3, s = j & 7;
            gload16(&A[(size_t)(bm + row) * K + k0 + ((s ^ (row & 7)) * 8)],
                    &sA[buf][(r * 256 + wave * 64) * 8]);
        }
        #pragma unroll
        for (int r = 0; r < NLDW; r++) {
            int j = r * 256 + tid;
            int row = j >> 3, s = j & 7;
            gload16(&W[(size_t)(bn + row) * K + k0 + ((s ^ (row & 7)) * 8)],
                    &sW[buf][(r * 256 + wave * 64) * 8]);
        }
    };

    f32x4 acc[FM][FN];
    #pragma unroll
    for (int i = 0; i < FM; i++)
        #pragma unroll
        for (int j = 0; j < FN; j++)
            acc[i][j] = (f32x4){0.f, 0.f, 0.f, 0.f};

    stage(0, 0);
    __syncthreads();
    int cur = 0;
    for (int k0 = 0; k0 < K; k0 += 64) {
        if (k0 + 64 < K) stage(cur ^ 1, k0 + 64);   // prefetch BEFORE compute
        #pragma unroll
        for (int kk = 0; kk < 2; kk++) {
            bf16x8 af[FM], wf[FN];
            #pragma unroll
            for (int i = 0; i < FM; i++) {
                int row = wrow + i * 16 + r16;
                af[i] = *(const bf16x8*)&sA[cur][row * 64 + (((kk * 4 + quad) ^ (row & 7)) * 8)];
            }
            #pragma unroll
            for (int j = 0; j < FN; j++) {
                int row = wcol + j * 16 + r16;
                wf[j] = *(const bf16x8*)&sW[cur][row * 64 + (((kk * 4 + quad) ^ (row & 7)) * 8)];
            }
            #pragma unroll
            for (int i = 0; i < FM; i++)
                #pragma unroll
                for (int j = 0; j < FN; j++)
                    acc[i][j] = __builtin_amdgcn_mfma_f32_16x16x32_bf16(
                        af[i], wf[j], acc[i][j], 0, 0, 0);
        }
        __syncthreads();     // single barrier: drains prefetch + read hazard
        cur ^= 1;
    }
    #pragma unroll
    for (int i = 0; i < FM; i++) {
        #pragma unroll
        for (int j = 0; j < FN; j++) {
            int col = bn + wcol + j * 16 + r16;
            #pragma unroll
            for (int reg = 0; reg < 4; reg++) {
                int row = bm + wrow + i * 16 + quad * 4 + reg;
                C[(size_t)row * N + col] = acc[i][j][reg];
            }
        }
    }
}

// ---------------- dt GEMM bf16 MFMA (M=2048, N=DI, K=64) --------------------
__global__ __launch_bounds__(256) void dt_gemm_bf16(
    const unsigned short* __restrict__ A,   // M x 64 (dbc_bf, cols 48+ = 0)
    const unsigned short* __restrict__ W,   // DI x 64 (wdt_bf layer)
    const float* __restrict__ bias,
    float* __restrict__ dtb) {
    __shared__ unsigned short sA[128 * 64];
    __shared__ unsigned short sW[128 * 64];
    int bm = blockIdx.y * 128, bn = blockIdx.x * 128;
    int tid = threadIdx.x;
    int wave = tid >> 6, lane = tid & 63;
    int wrow = (wave & 1) * 64, wcol = (wave >> 1) * 64;
    int quad = lane >> 4, r16 = lane & 15;
    f32x4 acc[4][4];
    #pragma unroll
    for (int i = 0; i < 4; i++)
        #pragma unroll
        for (int j = 0; j < 4; j++)
            acc[i][j] = (f32x4){0.f, 0.f, 0.f, 0.f};

    #pragma unroll
    for (int r = 0; r < 8; r++) {
        if (r < 4) {
            int j = r * 256 + tid;
            int row = j >> 3, s = j & 7;
            gload16(&A[(size_t)(bm + row) * KDT_ + ((s ^ (row & 7)) * 8)],
                    &sA[(r * 256 + wave * 64) * 8]);
        } else {
            int j = (r - 4) * 256 + tid;
            int row = j >> 3, s = j & 7;
            gload16(&W[(size_t)(bn + row) * KDT_ + ((s ^ (row & 7)) * 8)],
                    &sW[((r - 4) * 256 + wave * 64) * 8]);
        }
    }
    __syncthreads();
    #pragma unroll
    for (int kk = 0; kk < 2; kk++) {
        bf16x8 af[4], wf[4];
        #pragma unroll
        for (int i = 0; i < 4; i++) {
            int row = wrow + i * 16 + r16;
            af[i] = *(const bf16x8*)&sA[row * 64 + (((kk * 4 + quad) ^ (row & 7)) * 8)];
        }
        #pragma unroll
        for (int j = 0; j < 4; j++) {
            int row = wcol + j * 16 + r16;
            wf[j] = *(const bf16x8*)&sW[row * 64 + (((kk * 4 + quad) ^ (row & 7)) * 8)];
        }
        #pragma unroll
        for (int i = 0; i < 4; i++)
            #pragma unroll
            for (int j = 0; j < 4; j++)
                acc[i][j] = __builtin_amdgcn_mfma_f32_16x16x32_bf16(
                    af[i], wf[j], acc[i][j], 0, 0, 0);
    }
    #pragma unroll
    for (int i = 0; i < 4; i++) {
        #pragma unroll
        for (int j = 0; j < 4; j++) {
            int col = bn + wcol + j * 16 + r16;
            float bv = bias[col];
            #pragma unroll
            for (int reg = 0; reg < 4; reg++) {
                int row = bm + wrow + i * 16 + quad * 4 + reg;
                float v = acc[i][j][reg] + bv;
                v = (v > 20.f) ? v : log1pf(__expf(v));
                dtb[(size_t)row * DI_ + col] = v;
            }
        }
    }
}

// ---------------- fused conv+SiLU+x_proj GEMM (split-K over ks) -------------
// xz staging via regular float4 loads (REVERTED from gload16: the halo branch
// runs with partial exec, which violates gload16's wave-uniform-dest rule).
__global__ __launch_bounds__(256) void conv_xproj_kernel(
    const float* __restrict__ xz,
    const float* __restrict__ cw,
    const float* __restrict__ cb,
    const unsigned short* __restrict__ W,
    float* __restrict__ xcf,
    float* __restrict__ Pb) {
    __shared__ float sxz[67 * 96];
    __shared__ unsigned short sxcb[64 * 104];
    __shared__ float scw[96 * 4];
    __shared__ float scb[96];
    unsigned short* sW = (unsigned short*)sxz;

    int ks = blockIdx.x;
    int bm = blockIdx.y * 64;
    int tid = threadIdx.x;
    int b = bm >> 10, t0 = bm & (L_ - 1);
    int dbase = ks * KCH_;

    if (tid < 96) {
        int d = dbase + tid;
        *(float4*)&scw[tid * 4] = *(const float4*)&cw[d * 4];
        scb[tid] = cb[d];
    }
    for (int j = tid; j < 67 * 24; j += 256) {
        int r = j / 24, c4 = (j % 24) * 4;
        int tt = t0 + r - 3;
        float4 v = make_float4(0.f, 0.f, 0.f, 0.f);
        if (tt >= 0)
            v = *(const float4*)&xz[((size_t)(b * L_ + tt)) * (2 * DI_) + dbase + c4];
        *(float4*)&sxz[r * 96 + c4] = v;
    }
    __syncthreads();
    for (int j = tid; j < 64 * 96; j += 256) {
        int r = j / 96, c = j % 96;
        float acc = scb[c];
        #pragma unroll
        for (int k = 0; k < KC_; k++)
            acc = fmaf(scw[c * 4 + k], sxz[(r + k) * 96 + c], acc);
        float v = acc / (1.0f + __expf(-acc));
        xcf[(size_t)(bm + r) * DI_ + dbase + c] = v;
        sxcb[r * 104 + c] = f2bf(v);
    }
    __syncthreads();
    for (int j = tid; j < 80 * 12; j += 256) {
        int row = j / 12, c16 = (j % 12) * 8;
        *(uint4*)&sW[row * 104 + c16] =
            *(const uint4*)&W[(size_t)row * DI_ + dbase + c16];
    }
    __syncthreads();
    int wave = tid >> 6, lane = tid & 63;
    int quad = lane >> 4, r16 = lane & 15;
    f32x4 acc[5];
    #pragma unroll
    for (int j = 0; j < 5; j++) acc[j] = (f32x4){0.f, 0.f, 0.f, 0.f};
    #pragma unroll
    for (int kk = 0; kk < 3; kk++) {
        bf16x8 af = *(const bf16x8*)&sxcb[(wave * 16 + r16) * 104 + kk * 32 + quad * 8];
        #pragma unroll
        for (int j = 0; j < 5; j++) {
            bf16x8 wf = *(const bf16x8*)&sW[(j * 16 + r16) * 104 + kk * 32 + quad * 8];
            acc[j] = __builtin_amdgcn_mfma_f32_16x16x32_bf16(af, wf, acc[j], 0, 0, 0);
        }
    }
    #pragma unroll
    for (int j = 0; j < 5; j++) {
        int col = j * 16 + r16;
        #pragma unroll
        for (int reg = 0; reg < 4; reg++) {
            int row = bm + wave * 16 + quad * 4 + reg;
            Pb[((size_t)ks * M_ + row) * 80 + col] = acc[j][reg];
        }
    }
}

// reduce split-K partials; scatter into dbc_bf (M x 64 bf16) and packed BC
__global__ void xproj_reduce_kernel(const float* __restrict__ Pb,
                                    unsigned short* __restrict__ dbc_bf,
                                    float* __restrict__ bcp) {
    int i = blockIdx.x * 256 + threadIdx.x;   // over M_*80
    float s = 0.f;
    #pragma unroll
    for (int ks = 0; ks < KS_; ks++) s += Pb[(size_t)ks * (M_ * 80) + i];
    int m = i / 80, col = i % 80;
    if (col < DR_) {
        dbc_bf[m * KDT_ + col] = f2bf(s);
    } else if (col < DR_ + NS_) {
        bcp[m * 32 + 2 * (col - DR_)] = s;         // B_n
    } else {
        bcp[m * 32 + 2 * (col - DR_ - NS_) + 1] = s; // C_n
    }
}

// ---------------- scan pass A: per-chunk summaries (S[16] + sd scalar) ------
__global__ __launch_bounds__(128) void scan_ps_kernel(
    const float* __restrict__ dtb,
    const float* __restrict__ xcf,
    const float4* __restrict__ bcp4,
    const float* __restrict__ negA,
    float* __restrict__ Sb,
    float* __restrict__ sdb) {
    const int NDB = DI_ / 128;         // 12 d-blocks
    int bx = blockIdx.x;
    int dblk = bx % NDB;
    int c = (bx / NDB) % NC_;
    int b = bx / (NDB * NC_);
    int d = dblk * 128 + threadIdx.x;

    float A[NS_];
    #pragma unroll
    for (int n = 0; n < NS_; n++) A[n] = negA[(size_t)d * NS_ + n];
    float h[NS_];
    #pragma unroll
    for (int n = 0; n < NS_; n++) h[n] = 0.f;
    float sd = 0.f;

    size_t btbase = (size_t)(b * L_ + c * T_);
    const float* pdt = dtb + btbase * DI_ + d;
    const float* pxc = xcf + btbase * DI_ + d;
    const float4* pbc = bcp4 + btbase * 8;

    #pragma unroll 4
    for (int t = 0; t < T_; t++) {
        float dt = pdt[(size_t)t * DI_];
        float u  = dt * pxc[(size_t)t * DI_];
        sd += dt;
        #pragma unroll
        for (int q = 0; q < 8; q++) {
            float4 v = pbc[t * 8 + q];
            float e0 = __expf(dt * A[2 * q]);
            h[2 * q] = fmaf(e0, h[2 * q], u * v.x);
            float e1 = __expf(dt * A[2 * q + 1]);
            h[2 * q + 1] = fmaf(e1, h[2 * q + 1], u * v.z);
        }
    }

    size_t o = (((size_t)b * NC_ + c) * DI_ + d) * NS_;
    #pragma unroll
    for (int n = 0; n < NS_; n++) Sb[o + n] = h[n];
    sdb[((size_t)b * NC_ + c) * DI_ + d] = sd;
}

// ---------------- scan pass B: sequential combine, 4-deep pipeline ----------
__global__ __launch_bounds__(64) void scan_combine_kernel(
    const float* __restrict__ Sb, const float* __restrict__ sdb,
    const float* __restrict__ negA, float* __restrict__ hin) {
    int i = blockIdx.x * 64 + threadIdx.x;    // over B*DI*NS
    int b = i / (DI_ * NS_);
    int rem = i % (DI_ * NS_);
    int d = rem >> 4;                          // NS = 16
    float Aa = negA[rem];
    const size_t str = (size_t)DI_ * NS_;
    size_t o = (size_t)b * NC_ * str + rem;
    size_t osd = (size_t)b * NC_ * DI_ + d;
    float h = 0.f;
    float s0 = Sb[o],           sd0 = sdb[osd];
    float s1 = Sb[o + str],     sd1 = sdb[osd + DI_];
    float s2 = Sb[o + 2 * str], sd2 = sdb[osd + 2 * DI_];
    float s3 = Sb[o + 3 * str], sd3 = sdb[osd + 3 * DI_];
    for (int c = 0; c < NC_ - 4; c += 4) {
        float n0 = Sb[o + 4 * str], nd0 = sdb[osd + 4 * DI_];
        float n1 = Sb[o + 5 * str], nd1 = sdb[osd + 5 * DI_];
        float n2 = Sb[o + 6 * str], nd2 = sdb[osd + 6 * DI_];
        float n3 = Sb[o + 7 * str], nd3 = sdb[osd + 7 * DI_];
        hin[o] = h;           h = fmaf(__expf(Aa * sd0), h, s0);
        hin[o + str] = h;     h = fmaf(__expf(Aa * sd1), h, s1);
        hin[o + 2 * str] = h; h = fmaf(__expf(Aa * sd2), h, s2);
        hin[o + 3 * str] = h; h = fmaf(__expf(Aa * sd3), h, s3);
        s0 = n0; sd0 = nd0; s1 = n1; sd1 = nd1;
        s2 = n2; sd2 = nd2; s3 = n3; sd3 = nd3;
        o += 4 * str; osd += 4 * DI_;
    }
    hin[o] = h;           h = fmaf(__expf(Aa * sd0), h, s0);
    hin[o + str] = h;     h = fmaf(__expf(Aa * sd1), h, s1);
    hin[o + 2 * str] = h; h = fmaf(__expf(Aa * sd2), h, s2);
    hin[o + 3 * str] = h;
}

// ---------------- scan pass C: exact recurrence from hin -> yg --------------
__global__ __launch_bounds__(128) void scan_out_kernel(
    const float* __restrict__ dtb, const float* __restrict__ xcf,
    const float4* __restrict__ bcp4, const float* __restrict__ negA,
    const float* __restrict__ hin, const float* __restrict__ xz,
    const float* __restrict__ Dp, unsigned short* __restrict__ yg) {
    const int NDB = DI_ / 128;
    int bx = blockIdx.x;
    int dblk = bx % NDB;
    int c = (bx / NDB) % NC_;
    int b = bx / (NDB * NC_);
    int d = dblk * 128 + threadIdx.x;

    float A[NS_];
    #pragma unroll
    for (int n = 0; n < NS_; n++) A[n] = negA[(size_t)d * NS_ + n];
    size_t o = (((size_t)b * NC_ + c) * DI_ + d) * NS_;
    float h[NS_];
    #pragma unroll
    for (int n = 0; n < NS_; n++) h[n] = hin[o + n];
    float dpv = Dp[d];

    size_t btbase = (size_t)(b * L_ + c * T_);
    const float* pdt = dtb + btbase * DI_ + d;
    const float* pxc = xcf + btbase * DI_ + d;
    const float4* pbc = bcp4 + btbase * 8;

    #pragma unroll 4
    for (int t = 0; t < T_; t++) {
        float dt = pdt[(size_t)t * DI_];
        float xc = pxc[(size_t)t * DI_];
        float u = dt * xc;
        float y = 0.f;
        #pragma unroll
        for (int q = 0; q < 8; q++) {
            float4 v = pbc[t * 8 + q];
            float e0 = __expf(dt * A[2 * q]);
            h[2 * q] = fmaf(e0, h[2 * q], u * v.x);
            y = fmaf(v.y, h[2 * q], y);
            float e1 = __expf(dt * A[2 * q + 1]);
            h[2 * q + 1] = fmaf(e1, h[2 * q + 1], u * v.z);
            y = fmaf(v.w, h[2 * q + 1], y);
        }
        size_t row = btbase + t;
        float zv = xz[row * (2 * DI_) + DI_ + d];
        float yy = y + xc * dpv;
        yy *= zv / (1.0f + __expf(-zv));
        yg[row * DI_ + d] = f2bf(yy);
    }
}

extern "C" void kernel_launch(void* const* d_in, const int* in_sizes, int n_in,
                              void* d_out, int out_size, void* d_ws, size_t ws_size,
                              hipStream_t stream) {
    const float* x        = (const float*)d_in[0];
    const float* ln_w     = (const float*)d_in[1];
    const float* ln_b     = (const float*)d_in[2];
    const float* in_proj  = (const float*)d_in[3];
    const float* conv_w   = (const float*)d_in[4];
    const float* conv_b   = (const float*)d_in[5];
    const float* x_proj   = (const float*)d_in[6];
    const float* dt_w     = (const float*)d_in[7];
    const float* dt_b     = (const float*)d_in[8];
    const float* A_log    = (const float*)d_in[9];
    const float* D_skip   = (const float*)d_in[10];
    const float* out_proj = (const float*)d_in[11];
    const float* fn_w     = (const float*)d_in[12];
    const float* fn_b     = (const float*)d_in[13];
    float* out = (float*)d_out;

    char* p = (char*)d_ws;
    auto alloc = [&](size_t bytes) {
        char* r = p;
        p += (bytes + 255) & ~(size_t)255;
        return (void*)r;
    };
    float* xcur = (float*)alloc((size_t)M_ * D_ * 4);
    float* res  = (float*)alloc((size_t)M_ * D_ * 4);
    unsigned short* xn = (unsigned short*)alloc((size_t)M_ * D_ * 2);
    float* xz   = (float*)alloc((size_t)M_ * 2 * DI_ * 4);
    float* dtb  = (float*)alloc((size_t)M_ * DI_ * 4);
    float* xcf  = (float*)alloc((size_t)M_ * DI_ * 4);
    unsigned short* dbc_bf = (unsigned short*)alloc((size_t)M_ * KDT_ * 2);
    float* bcp  = (float*)alloc((size_t)M_ * 32 * 4);
    unsigned short* yg = (unsigned short*)alloc((size_t)M_ * DI_ * 2);
    float* Sb   = (float*)alloc((size_t)B_ * NC_ * DI_ * NS_ * 4);   // 6.3 MB
    float* sdb  = (float*)alloc((size_t)B_ * NC_ * DI_ * 4);         // 0.4 MB
    float* hin  = (float*)alloc((size_t)B_ * NC_ * DI_ * NS_ * 4);
    float* Pb   = (float*)alloc((size_t)KS_ * M_ * 80 * 4);
    float* negA = (float*)alloc((size_t)NL_ * DI_ * NS_ * 4);
    const size_t n_wi = (size_t)NL_ * 2 * DI_ * D_;
    const size_t n_wo = (size_t)NL_ * D_ * DI_;
    const size_t n_wx = (size_t)NL_ * 80 * DI_;
    const size_t n_wdt = (size_t)NL_ * DI_ * KDT_;
    unsigned short* wi_bf = (unsigned short*)alloc(n_wi * 2);
    unsigned short* wo_bf = (unsigned short*)alloc(n_wo * 2);
    unsigned short* wx_bf = (unsigned short*)alloc(n_wx * 2);
    unsigned short* wdt_bf = (unsigned short*)alloc(n_wdt * 2);

    prep_kernel<<<7808, 256, 0, stream>>>(
        in_proj, wi_bf, out_proj, wo_bf, x_proj, wx_bf,
        dt_w, wdt_bf, A_log, negA, x, xcur, res, dbc_bf);

    for (int l = 0; l < NL_; l++) {
        const float* negA_l = negA + (size_t)l * DI_ * NS_;

        ln_res_kernel<<<M_ / 4, 256, 0, stream>>>(
            xcur, res, ln_w + l * D_, ln_b + l * D_, xn);

        // xz = xn @ Wi^T  (M=2048, N=3072, K=768): 128x64 -> 768 blocks (3/CU)
        gemm_bf16_t<128, 64><<<dim3((2 * DI_) / 64, M_ / 128), 256, 0, stream>>>(
            xn, wi_bf + (size_t)l * 2 * DI_ * D_, xz, M_, 2 * DI_, D_);

        conv_xproj_kernel<<<dim3(KS_, M_ / 64), 256, 0, stream>>>(
            xz, conv_w + l * DI_ * KC_, conv_b + l * DI_,
            wx_bf + (size_t)l * 80 * DI_, xcf, Pb);
        xproj_reduce_kernel<<<(M_ * 80) / 256, 256, 0, stream>>>(Pb, dbc_bf, bcp);

        dt_gemm_bf16<<<dim3(DI_ / 128, M_ / 128), 256, 0, stream>>>(
            dbc_bf, wdt_bf + (size_t)l * DI_ * KDT_, dt_b + l * DI_, dtb);

        scan_ps_kernel<<<B_ * NC_ * (DI_ / 128), 128, 0, stream>>>(
            dtb, xcf, (const float4*)bcp, negA_l, Sb, sdb);
        scan_combine_kernel<<<(B_ * DI_ * NS_) / 64, 64, 0, stream>>>(
            Sb, sdb, negA_l, hin);
        scan_out_kernel<<<B_ * NC_ * (DI_ / 128), 128, 0, stream>>>(
            dtb, xcf, (const float4*)bcp, negA_l, hin, xz,
            D_skip + (size_t)l * DI_, yg);

        // xcur = yg @ Wo^T  (M=2048, N=768, K=1536): 64x64 -> 384 blocks
        gemm_bf16_t<64, 64><<<dim3(D_ / 64, M_ / 64), 256, 0, stream>>>(
            yg, wo_bf + (size_t)l * D_ * DI_, xcur, M_, D_, DI_);
    }

    final_ln_kernel<<<M_ / 4, 256, 0, stream>>>(xcur, res, fn_w, fn_b, out);
}